// Round 1
// baseline (681.407 us; speedup 1.0000x reference)
//
#include <hip/hip_runtime.h>

constexpr int B = 32, S = 255, H = 1024, BS = 120, O = 10, WD = 20;
constexpr int HSZ = 2*(BS+1) + WD;   // 262
constexpr int R  = B*S;              // 8160
constexpr int RO = R*O;              // 81600

// ---------------------------------------------------------------------------
// K1: h = leaky(state @ head_w + head_b), t = leaky(state @ tail_w + tail_b)
// GEMM M=8160 N=120(pad128) K=1024. BM=64 BN=128 BK=32, 256 thr, tile 8x4.
// ---------------------------------------------------------------------------
__global__ __launch_bounds__(256) void ht_kernel(
    const float* __restrict__ state,
    const float* __restrict__ head_w, const float* __restrict__ head_b,
    const float* __restrict__ tail_w, const float* __restrict__ tail_b,
    float* __restrict__ hbuf, float* __restrict__ tbuf)
{
    __shared__ float As[64*36];    // 64 rows x 32 k, pad 36 (16B-aligned rows)
    __shared__ float Ws[32*132];   // 32 k x 128 cols, pad 132
    const int r0 = blockIdx.x * 64;
    const int is_tail = blockIdx.y;
    const float* Wg = is_tail ? tail_w : head_w;
    const float* bg = is_tail ? tail_b : head_b;
    float* Cg = is_tail ? tbuf : hbuf;
    const int tid = threadIdx.x;
    const int ty = tid >> 5, tx = tid & 31;   // 8 x 32

    float acc[8][4];
    #pragma unroll
    for (int i = 0; i < 8; ++i)
        #pragma unroll
        for (int c = 0; c < 4; ++c) acc[i][c] = 0.f;

    for (int k0 = 0; k0 < H; k0 += 32) {
        #pragma unroll
        for (int l = 0; l < 8; ++l) {
            int idx = tid + l*256;
            int row = idx >> 5, col = idx & 31;
            int r = r0 + row;
            As[row*36 + col] = (r < R) ? state[r*H + k0 + col] : 0.f;
        }
        #pragma unroll
        for (int l = 0; l < 16; ++l) {
            int idx = tid + l*256;
            int kk = idx >> 7, c = idx & 127;
            Ws[kk*132 + c] = (c < BS) ? Wg[(k0+kk)*BS + c] : 0.f;
        }
        __syncthreads();
        #pragma unroll
        for (int k4 = 0; k4 < 32; k4 += 4) {
            float av[8][4], bv[4][4];
            #pragma unroll
            for (int i = 0; i < 8; ++i)
                *(float4*)av[i] = *(const float4*)&As[(ty*8+i)*36 + k4];
            #pragma unroll
            for (int kk = 0; kk < 4; ++kk)
                *(float4*)bv[kk] = *(const float4*)&Ws[(k4+kk)*132 + tx*4];
            #pragma unroll
            for (int i = 0; i < 8; ++i)
                #pragma unroll
                for (int kk = 0; kk < 4; ++kk)
                    #pragma unroll
                    for (int c = 0; c < 4; ++c)
                        acc[i][c] += av[i][kk] * bv[kk][c];
        }
        __syncthreads();
    }
    const int c0 = tx*4;
    if (c0 < BS) {
        float bb[4];
        *(float4*)bb = *(const float4*)&bg[c0];
        #pragma unroll
        for (int i = 0; i < 8; ++i) {
            int r = r0 + ty*8 + i;
            if (r < R) {
                float v[4];
                #pragma unroll
                for (int c = 0; c < 4; ++c) {
                    float z = acc[i][c] + bb[c];
                    v[c] = (z >= 0.f) ? z : 0.01f*z;
                }
                *(float4*)&Cg[r*BS + c0] = *(float4*)v;
            }
        }
    }
}

// ---------------------------------------------------------------------------
// K2: hU[r][o][j] = sum_i h[r][i] * U[o][i][j].  grid (255 row-blocks, 10 o).
// 128 thr (4x32), 32 rows/block, thread tile 8 rows x 4 cols, K=120 full.
// ---------------------------------------------------------------------------
__global__ __launch_bounds__(128) void hU_kernel(
    const float* __restrict__ hbuf, const float* __restrict__ U,
    float* __restrict__ hU)
{
    __shared__ float hs[32*124];    // 32 rows x 120 k, pad 124
    __shared__ float Us[120*132];   // 120 k x 128 cols, pad 132
    const int r0 = blockIdx.x * 32;
    const int o  = blockIdx.y;
    const int tid = threadIdx.x;
    for (int idx = tid; idx < 32*120; idx += 128) {
        int row = idx / 120, col = idx - row*120;
        hs[row*124 + col] = hbuf[(r0+row)*BS + col];
    }
    for (int idx = tid; idx < 120*128; idx += 128) {
        int kk = idx >> 7, c = idx & 127;
        Us[kk*132 + c] = (c < BS) ? U[(o*BS + kk)*BS + c] : 0.f;
    }
    __syncthreads();
    const int ty = tid >> 5, tx = tid & 31;   // 4 x 32
    float acc[8][4];
    #pragma unroll
    for (int i = 0; i < 8; ++i)
        #pragma unroll
        for (int c = 0; c < 4; ++c) acc[i][c] = 0.f;

    for (int k0 = 0; k0 < BS; k0 += 4) {
        float av[8][4], bv[4][4];
        #pragma unroll
        for (int i = 0; i < 8; ++i)
            *(float4*)av[i] = *(const float4*)&hs[(ty*8+i)*124 + k0];
        #pragma unroll
        for (int kk = 0; kk < 4; ++kk)
            *(float4*)bv[kk] = *(const float4*)&Us[(k0+kk)*132 + tx*4];
        #pragma unroll
        for (int i = 0; i < 8; ++i)
            #pragma unroll
            for (int kk = 0; kk < 4; ++kk)
                #pragma unroll
                for (int c = 0; c < 4; ++c)
                    acc[i][c] += av[i][kk] * bv[kk][c];
    }
    const int c0 = tx*4;
    if (c0 < BS) {
        #pragma unroll
        for (int i = 0; i < 8; ++i) {
            int r = r0 + ty*8 + i;   // always < 8160 (255*32)
            float v[4];
            #pragma unroll
            for (int c = 0; c < 4; ++c) v[c] = acc[i][c];
            *(float4*)&hU[(size_t)r*(O*BS) + o*BS + c0] = *(float4*)v;
        }
    }
}

// ---------------------------------------------------------------------------
// K3: hw[r][o] = h1 . Wh[o] + cls_b[o];  tw[r][o] = t1 . Wt[o];
//     tbl[p][o] = width_table[p] . Ww[o]
// ---------------------------------------------------------------------------
__global__ __launch_bounds__(256) void small_kernel(
    const float* __restrict__ hbuf, const float* __restrict__ tbuf,
    const float* __restrict__ wtab, const float* __restrict__ cls_w,
    const float* __restrict__ cls_b,
    float* __restrict__ hw, float* __restrict__ tw, float* __restrict__ tbl)
{
    const int gid = blockIdx.x * 256 + threadIdx.x;
    if (blockIdx.x < 638) {
        if (gid >= 2*RO) return;
        const int which = gid / RO;
        const int rem = gid - which*RO;
        const int r = rem / O, o = rem - (rem/O)*O;
        const float* src  = (which ? tbuf : hbuf) + (size_t)r*BS;
        const float* wrow = cls_w + o*HSZ + which*(BS+1);
        float s = 0.f;
        for (int i = 0; i < BS; ++i) s += src[i]*wrow[i];
        s += wrow[BS];               // the appended "ones" column
        if (!which) { s += cls_b[o]; hw[r*O+o] = s; }
        else        { tw[r*O+o] = s; }
    } else {
        const int id = gid - 638*256;
        if (id >= 256*O) return;
        const int p = id / O, o = id - (id/O)*O;
        float s = 0.f;
        for (int w = 0; w < WD; ++w)
            s += wtab[p*WD + w] * cls_w[o*HSZ + 2*(BS+1) + w];
        tbl[p*O + o] = s;
    }
}

// ---------------------------------------------------------------------------
// K4: out[b,x,y,o] = dot120(hU[b,x,o,:], t[b,y,:]) + hw[b,x,o] + tw[b,y,o]
//                    + tbl[clamp(y-x+1,0),o]
// grid (b=32, xt=32, yt=2). block 256 = (xg 8) x (yq 32); thread: 1 x, 4 y, 10 o.
// ---------------------------------------------------------------------------
__global__ __launch_bounds__(256) void main_kernel(
    const float* __restrict__ hU, const float* __restrict__ tbuf,
    const float* __restrict__ hw, const float* __restrict__ tw,
    const float* __restrict__ tbl, float* __restrict__ out)
{
    __shared__ float hUs[8*1200];     // 38.4 KB : hU[x-tile][o][j] flat
    __shared__ float tsT[120*132];    // 63.4 KB : t transposed [j][y], pad 132
    const int b  = blockIdx.x;
    const int x0 = blockIdx.y * 8;
    const int y0 = blockIdx.z * 128;
    const int tid = threadIdx.x;

    for (int idx = tid; idx < 8*1200; idx += 256) {
        int xx = idx / 1200;
        int x = x0 + xx;
        hUs[idx] = (x < S) ? hU[(size_t)(b*S + x)*1200 + (idx - xx*1200)] : 0.f;
    }
    for (int idx = tid; idx < 128*120; idx += 256) {
        int yy = idx / 120, j = idx - yy*120;
        int y = y0 + yy;
        tsT[j*132 + yy] = (y < S) ? tbuf[(size_t)(b*S + y)*BS + j] : 0.f;
    }
    __syncthreads();

    const int xg = tid >> 5, yq = tid & 31;
    const int x = x0 + xg;
    const int ybase = y0 + yq*4;

    float acc[4][10];
    #pragma unroll
    for (int yy = 0; yy < 4; ++yy)
        #pragma unroll
        for (int o = 0; o < 10; ++o) acc[yy][o] = 0.f;

    for (int j0 = 0; j0 < BS; j0 += 4) {
        float tv[4][4];   // [jj][yy]
        #pragma unroll
        for (int jj = 0; jj < 4; ++jj)
            *(float4*)tv[jj] = *(const float4*)&tsT[(j0+jj)*132 + yq*4];
        #pragma unroll
        for (int o = 0; o < 10; ++o) {
            float hv[4];
            *(float4*)hv = *(const float4*)&hUs[xg*1200 + o*120 + j0];
            #pragma unroll
            for (int jj = 0; jj < 4; ++jj)
                #pragma unroll
                for (int yy = 0; yy < 4; ++yy)
                    acc[yy][o] += hv[jj] * tv[jj][yy];
        }
    }

    if (x >= S) return;
    float hwv[10];
    #pragma unroll
    for (int o = 0; o < 10; ++o) hwv[o] = hw[(b*S+x)*O + o];

    #pragma unroll
    for (int yy = 0; yy < 4; ++yy) {
        const int y = ybase + yy;
        if (y < S) {
            int p = y - x + 1; if (p < 0) p = 0;
            const float* tb  = &tbl[p*O];
            const float* twp = &tw[(size_t)(b*S+y)*O];
            float* op = &out[((size_t)(b*S+x)*S + y)*O];
            #pragma unroll
            for (int o = 0; o < 10; o += 2) {
                float2 v;
                v.x = acc[yy][o]   + hwv[o]   + twp[o]   + tb[o];
                v.y = acc[yy][o+1] + hwv[o+1] + twp[o+1] + tb[o+1];
                *(float2*)&op[o] = v;
            }
        }
    }
}

// ---------------------------------------------------------------------------
extern "C" void kernel_launch(void* const* d_in, const int* in_sizes, int n_in,
                              void* d_out, int out_size, void* d_ws, size_t ws_size,
                              hipStream_t stream)
{
    const float* state  = (const float*)d_in[0];
    const float* head_w = (const float*)d_in[1];
    const float* head_b = (const float*)d_in[2];
    const float* tail_w = (const float*)d_in[3];
    const float* tail_b = (const float*)d_in[4];
    const float* U      = (const float*)d_in[5];
    const float* wtab   = (const float*)d_in[6];
    const float* cls_w  = (const float*)d_in[7];
    const float* cls_b  = (const float*)d_in[8];
    float* out = (float*)d_out;

    float* ws   = (float*)d_ws;
    float* hbuf = ws;                              // R*BS      = 979200
    float* tbuf = hbuf + (size_t)R*BS;             // R*BS
    float* hU   = tbuf + (size_t)R*BS;             // R*O*BS    = 9792000
    float* hw   = hU   + (size_t)R*O*BS;           // RO
    float* tw   = hw   + RO;                       // RO
    float* tbl  = tw   + RO;                       // 256*O     (total ~47.7 MB)

    hipLaunchKernelGGL(ht_kernel, dim3(128,2), dim3(256), 0, stream,
                       state, head_w, head_b, tail_w, tail_b, hbuf, tbuf);
    hipLaunchKernelGGL(hU_kernel, dim3(255,10), dim3(128), 0, stream,
                       hbuf, U, hU);
    hipLaunchKernelGGL(small_kernel, dim3(648), dim3(256), 0, stream,
                       hbuf, tbuf, wtab, cls_w, cls_b, hw, tw, tbl);
    hipLaunchKernelGGL(main_kernel, dim3(32,32,2), dim3(256), 0, stream,
                       hU, tbuf, hw, tw, tbl, out);
}

// Round 2
// 97.062 us; speedup vs baseline: 7.0203x; 7.0203x over previous
//
#include <hip/hip_runtime.h>
#include <hip/hip_bf16.h>

using f32x4 = __attribute__((ext_vector_type(4))) float;
using f32x2 = __attribute__((ext_vector_type(2))) float;
using s16x8 = __attribute__((ext_vector_type(8))) short;
using s16x4 = __attribute__((ext_vector_type(4))) short;

constexpr int S = 255, RTOT = 32 * 255;          // 8160
constexpr int NHW = 8160 * 12;

__device__ inline unsigned short f2bf(float x) {
    __hip_bfloat16 b = __float2bfloat16(x);      // RNE
    return __builtin_bit_cast(unsigned short, b);
}
__device__ inline float bf2f(unsigned short u) {
    unsigned int t = ((unsigned int)u) << 16;
    return __builtin_bit_cast(float, t);
}
__device__ inline f32x4 mfma16(s16x8 a, s16x8 b, f32x4 c) {
    return __builtin_amdgcn_mfma_f32_16x16x32_bf16(a, b, c, 0, 0, 0);
}

// ---------------------------------------------------------------------------
// K0: weight conversion.  Wt[n][k] (n pad 128), Ut[o][j][i] (j,i pad 128).
// ---------------------------------------------------------------------------
__global__ __launch_bounds__(256) void convert_k(
    const float* __restrict__ head_w, const float* __restrict__ tail_w,
    const float* __restrict__ U,
    unsigned short* __restrict__ WtH, unsigned short* __restrict__ WtT,
    unsigned short* __restrict__ Ut)
{
    int gid = blockIdx.x * 256 + threadIdx.x;
    if (gid < 131072) {
        int k = gid >> 7, n = gid & 127;
        float v = (n < 120) ? head_w[k * 120 + n] : 0.f;
        WtH[(size_t)n * 1024 + k] = f2bf(v);
    } else if (gid < 262144) {
        int idx = gid - 131072;
        int k = idx >> 7, n = idx & 127;
        float v = (n < 120) ? tail_w[k * 120 + n] : 0.f;
        WtT[(size_t)n * 1024 + k] = f2bf(v);
    } else {
        int idx = gid - 262144;
        if (idx < 163840) {
            int o = idx >> 14, rem = idx & 16383;
            int j = rem >> 7, i2 = rem & 127;
            float v = (i2 < 120 && j < 120) ? U[((size_t)o * 120 + i2) * 120 + j] : 0.f;
            Ut[(size_t)o * 16384 + (size_t)j * 128 + i2] = f2bf(v);
        }
    }
}

// ---------------------------------------------------------------------------
// K1: h/t = leaky(state @ W + b) via MFMA.  a=Wt (rows n), b=state (cols r).
// grid (128 r-blocks of 64, 2).  LDS: state 64x64, Wt 128x64, XOR-swizzled.
// ---------------------------------------------------------------------------
__global__ __launch_bounds__(256) void ht_mfma(
    const float* __restrict__ state,
    const unsigned short* __restrict__ WtH, const unsigned short* __restrict__ WtT,
    const float* __restrict__ head_b, const float* __restrict__ tail_b,
    unsigned short* __restrict__ hbuf, unsigned short* __restrict__ tbuf)
{
    __shared__ unsigned short Ss[64 * 64];
    __shared__ unsigned short Ws[128 * 64];
    const int r0 = blockIdx.x * 64;
    const unsigned short* Wt = blockIdx.y ? WtT : WtH;
    const float* bias = blockIdx.y ? tail_b : head_b;
    unsigned short* Cb = blockIdx.y ? tbuf : hbuf;
    const int tid = threadIdx.x;
    const int w = tid >> 6, lane = tid & 63;
    const int l16 = lane & 15, kq = lane >> 4;
    char* SsB = (char*)Ss;
    char* WsB = (char*)Ws;

    f32x4 acc[8];
    #pragma unroll
    for (int i = 0; i < 8; ++i) acc[i] = (f32x4){0.f, 0.f, 0.f, 0.f};

    for (int k0 = 0; k0 < 1024; k0 += 64) {
        #pragma unroll
        for (int i = 0; i < 2; ++i) {          // state 64r x 64k -> bf16
            int idx = i * 256 + tid;
            int row = idx >> 3, kc = idx & 7;
            int r = r0 + row;
            float v[8];
            if (r < RTOT) {
                *(f32x4*)&v[0] = *(const f32x4*)&state[(size_t)r * 1024 + k0 + kc * 8];
                *(f32x4*)&v[4] = *(const f32x4*)&state[(size_t)r * 1024 + k0 + kc * 8 + 4];
            } else {
                #pragma unroll
                for (int e = 0; e < 8; ++e) v[e] = 0.f;
            }
            s16x8 pk;
            #pragma unroll
            for (int e = 0; e < 8; ++e) pk[e] = (short)f2bf(v[e]);
            *(s16x8*)(SsB + row * 128 + ((kc * 16) ^ ((row & 7) << 4))) = pk;
        }
        #pragma unroll
        for (int i = 0; i < 4; ++i) {          // Wt 128n x 64k
            int idx = i * 256 + tid;
            int n = idx >> 3, kc = idx & 7;
            s16x8 pk = *(const s16x8*)&Wt[(size_t)n * 1024 + k0 + kc * 8];
            *(s16x8*)(WsB + n * 128 + ((kc * 16) ^ ((n & 7) << 4))) = pk;
        }
        __syncthreads();
        #pragma unroll
        for (int ks = 0; ks < 2; ++ks) {
            const int kb = ks * 64 + kq * 16;
            const int srow = w * 16 + l16;
            s16x8 bfrag = *(const s16x8*)(SsB + srow * 128 + (kb ^ ((srow & 7) << 4)));
            #pragma unroll
            for (int fn = 0; fn < 8; ++fn) {
                int n = fn * 16 + l16;
                s16x8 afrag = *(const s16x8*)(WsB + n * 128 + (kb ^ ((n & 7) << 4)));
                acc[fn] = mfma16(afrag, bfrag, acc[fn]);
            }
        }
        __syncthreads();
    }
    const int r = r0 + w * 16 + l16;
    if (r < RTOT) {
        #pragma unroll
        for (int fn = 0; fn < 8; ++fn) {
            int n0 = fn * 16 + kq * 4;
            s16x4 pk;
            #pragma unroll
            for (int e = 0; e < 4; ++e) {
                float bv = (n0 + e < 120) ? bias[n0 + e] : 0.f;
                float z = acc[fn][e] + bv;
                z = (z >= 0.f) ? z : 0.01f * z;
                pk[e] = (short)f2bf(z);
            }
            *(s16x4*)&Cb[(size_t)r * 128 + n0] = pk;
        }
    }
}

// ---------------------------------------------------------------------------
// K2: hU[r][o][j] = sum_i h[r][i] U[o][i][j].  a=Ut[o] (rows j), b=h (cols r).
// grid (64 r-blocks of 128, 10 o).  LDS: 2 x 128x128 bf16 swizzled (64 KB).
// ---------------------------------------------------------------------------
__global__ __launch_bounds__(256) void hU_mfma(
    const unsigned short* __restrict__ hbuf, const unsigned short* __restrict__ Ut,
    unsigned short* __restrict__ hU)
{
    __shared__ unsigned short Hs[128 * 128];
    __shared__ unsigned short Us[128 * 128];
    const int r0 = blockIdx.x * 128;
    const int o = blockIdx.y;
    const int tid = threadIdx.x;
    const int w = tid >> 6, lane = tid & 63;
    const int l16 = lane & 15, kq = lane >> 4;
    char* HsB = (char*)Hs;
    char* UsB = (char*)Us;

    #pragma unroll
    for (int i = 0; i < 8; ++i) {
        int idx = i * 256 + tid;
        int row = idx >> 4, kc = idx & 15;
        int r = r0 + row;
        s16x8 pk = {0, 0, 0, 0, 0, 0, 0, 0};
        if (r < RTOT) pk = *(const s16x8*)&hbuf[(size_t)r * 128 + kc * 8];
        *(s16x8*)(HsB + row * 256 + ((kc * 16) ^ ((row & 7) << 4))) = pk;
        s16x8 pu = *(const s16x8*)&Ut[(size_t)o * 16384 + (size_t)row * 128 + kc * 8];
        *(s16x8*)(UsB + row * 256 + ((kc * 16) ^ ((row & 7) << 4))) = pu;
    }
    __syncthreads();

    f32x4 acc[2][8];
    #pragma unroll
    for (int a = 0; a < 2; ++a)
        #pragma unroll
        for (int b2 = 0; b2 < 8; ++b2) acc[a][b2] = (f32x4){0.f, 0.f, 0.f, 0.f};

    #pragma unroll
    for (int ks = 0; ks < 4; ++ks) {
        int kb = ks * 64 + kq * 16;
        s16x8 bf[2];
        #pragma unroll
        for (int fr = 0; fr < 2; ++fr) {
            int row = w * 32 + fr * 16 + l16;
            bf[fr] = *(const s16x8*)(HsB + row * 256 + (kb ^ ((row & 7) << 4)));
        }
        #pragma unroll
        for (int fj = 0; fj < 8; ++fj) {
            int j = fj * 16 + l16;
            s16x8 af = *(const s16x8*)(UsB + j * 256 + (kb ^ ((j & 7) << 4)));
            #pragma unroll
            for (int fr = 0; fr < 2; ++fr)
                acc[fr][fj] = mfma16(af, bf[fr], acc[fr][fj]);
        }
    }

    #pragma unroll
    for (int fr = 0; fr < 2; ++fr) {
        int r = r0 + w * 32 + fr * 16 + l16;
        if (r < RTOT) {
            #pragma unroll
            for (int fj = 0; fj < 8; ++fj) {
                int j0 = fj * 16 + kq * 4;
                s16x4 pk;
                #pragma unroll
                for (int e = 0; e < 4; ++e) pk[e] = (short)f2bf(acc[fr][fj][e]);
                *(s16x4*)&hU[((size_t)r * 12 + o) * 128 + j0] = pk;
            }
        }
    }
}

// ---------------------------------------------------------------------------
// K3: hw[r][12], tw[r][12], tbl[256][12] fp32 (pads = 0)
// ---------------------------------------------------------------------------
__global__ __launch_bounds__(256) void small_k(
    const unsigned short* __restrict__ hbuf, const unsigned short* __restrict__ tbuf,
    const float* __restrict__ wtab, const float* __restrict__ cls_w,
    const float* __restrict__ cls_b,
    float* __restrict__ hwp, float* __restrict__ twp, float* __restrict__ tblp)
{
    const int gid = blockIdx.x * 256 + threadIdx.x;
    if (gid < 2 * NHW) {
        int which = gid >= NHW;
        int rem = which ? gid - NHW : gid;
        int r = rem / 12, o = rem % 12;
        float s = 0.f;
        if (o < 10) {
            const unsigned short* src = (which ? tbuf : hbuf) + (size_t)r * 128;
            const float* wrow = cls_w + o * 262 + which * 121;
            #pragma unroll
            for (int c = 0; c < 15; ++c) {
                s16x8 v = *(const s16x8*)&src[c * 8];
                #pragma unroll
                for (int e = 0; e < 8; ++e)
                    s += bf2f((unsigned short)v[e]) * wrow[c * 8 + e];
            }
            s += wrow[120];                       // "ones" column
            if (!which) s += cls_b[o];
        }
        if (which) twp[rem] = s; else hwp[rem] = s;
    } else {
        int id = gid - 2 * NHW;
        if (id < 256 * 12) {
            int p = id / 12, o = id % 12;
            float s = 0.f;
            if (o < 10) {
                for (int wq = 0; wq < 20; ++wq)
                    s += wtab[p * 20 + wq] * cls_w[o * 262 + 242 + wq];
            }
            tblp[id] = s;
        }
    }
}

// ---------------------------------------------------------------------------
// K4: out = hU[b] @ t[b]^T + hw + tw + tbl.  M=3060(pad3072) N=255 K=128.
// grid (24 m-tiles, 2 y-tiles, 32 b). 4 waves 2x2, 64x64 each.
// ---------------------------------------------------------------------------
__global__ __launch_bounds__(256) void main_mfma(
    const unsigned short* __restrict__ hU, const unsigned short* __restrict__ tbuf,
    const float* __restrict__ hwp, const float* __restrict__ twp,
    const float* __restrict__ tblp, float* __restrict__ out)
{
    __shared__ unsigned short As[128 * 128];
    __shared__ unsigned short Bs[128 * 128];
    const int m0 = blockIdx.x * 128, y0 = blockIdx.y * 128, b = blockIdx.z;
    const int tid = threadIdx.x;
    const int w = tid >> 6, lane = tid & 63;
    const int l16 = lane & 15, kq = lane >> 4;
    const int wm = w >> 1, wy = w & 1;
    char* AsB = (char*)As;
    char* BsB = (char*)Bs;

    #pragma unroll
    for (int i = 0; i < 8; ++i) {
        int idx = i * 256 + tid;
        int row = idx >> 4, kc = idx & 15;
        int m = m0 + row;
        s16x8 pa = {0, 0, 0, 0, 0, 0, 0, 0};
        if (m < 3060) pa = *(const s16x8*)&hU[((size_t)b * 3060 + m) * 128 + kc * 8];
        *(s16x8*)(AsB + row * 256 + ((kc * 16) ^ ((row & 7) << 4))) = pa;
        int y = y0 + row;
        s16x8 pb = {0, 0, 0, 0, 0, 0, 0, 0};
        if (y < S) pb = *(const s16x8*)&tbuf[((size_t)b * S + y) * 128 + kc * 8];
        *(s16x8*)(BsB + row * 256 + ((kc * 16) ^ ((row & 7) << 4))) = pb;
    }
    __syncthreads();

    f32x4 acc[4][4];
    #pragma unroll
    for (int a = 0; a < 4; ++a)
        #pragma unroll
        for (int c = 0; c < 4; ++c) acc[a][c] = (f32x4){0.f, 0.f, 0.f, 0.f};

    #pragma unroll
    for (int ks = 0; ks < 4; ++ks) {
        int kb = ks * 64 + kq * 16;
        s16x8 af[4], bf[4];
        #pragma unroll
        for (int fm = 0; fm < 4; ++fm) {
            int row = wm * 64 + fm * 16 + l16;
            af[fm] = *(const s16x8*)(AsB + row * 256 + (kb ^ ((row & 7) << 4)));
        }
        #pragma unroll
        for (int fy = 0; fy < 4; ++fy) {
            int row = wy * 64 + fy * 16 + l16;
            bf[fy] = *(const s16x8*)(BsB + row * 256 + (kb ^ ((row & 7) << 4)));
        }
        #pragma unroll
        for (int fm = 0; fm < 4; ++fm)
            #pragma unroll
            for (int fy = 0; fy < 4; ++fy)
                acc[fm][fy] = mfma16(af[fm], bf[fy], acc[fm][fy]);
    }

    #pragma unroll
    for (int fm = 0; fm < 4; ++fm) {
        int ml = m0 + wm * 64 + fm * 16 + kq * 4;      // 4 consecutive m rows
        if (ml >= 3060) continue;
        int x = ml / 12, o0 = ml % 12;                 // o0 in {0,4,8}
        if (o0 >= 10) continue;
        int rx = b * S + x;
        f32x4 hv = *(const f32x4*)&hwp[(size_t)rx * 12 + o0];
        #pragma unroll
        for (int fy = 0; fy < 4; ++fy) {
            int y = y0 + wy * 64 + fy * 16 + l16;
            if (y >= S) continue;
            int ry = b * S + y;
            f32x4 tv = *(const f32x4*)&twp[(size_t)ry * 12 + o0];
            int p = y - x + 1; if (p < 0) p = 0;
            f32x4 wv = *(const f32x4*)&tblp[p * 12 + o0];
            float* op = &out[((size_t)rx * S + y) * 10 + o0];
            f32x2 v01 = {acc[fm][fy][0] + hv[0] + tv[0] + wv[0],
                         acc[fm][fy][1] + hv[1] + tv[1] + wv[1]};
            *(f32x2*)op = v01;
            if (o0 < 8) {
                f32x2 v23 = {acc[fm][fy][2] + hv[2] + tv[2] + wv[2],
                             acc[fm][fy][3] + hv[3] + tv[3] + wv[3]};
                *(f32x2*)(op + 2) = v23;
            }
        }
    }
}

// ---------------------------------------------------------------------------
extern "C" void kernel_launch(void* const* d_in, const int* in_sizes, int n_in,
                              void* d_out, int out_size, void* d_ws, size_t ws_size,
                              hipStream_t stream)
{
    (void)in_sizes; (void)n_in; (void)out_size; (void)ws_size;
    const float* state  = (const float*)d_in[0];
    const float* head_w = (const float*)d_in[1];
    const float* head_b = (const float*)d_in[2];
    const float* tail_w = (const float*)d_in[3];
    const float* tail_b = (const float*)d_in[4];
    const float* U      = (const float*)d_in[5];
    const float* wtab   = (const float*)d_in[6];
    const float* cls_w  = (const float*)d_in[7];
    const float* cls_b  = (const float*)d_in[8];
    float* out = (float*)d_out;

    unsigned short* u16 = (unsigned short*)d_ws;
    unsigned short* hbuf = u16;                    // 8160*128
    unsigned short* tbuf = hbuf + 1044480;
    unsigned short* hUb  = tbuf + 1044480;         // 8160*12*128
    unsigned short* WtH  = hUb + 12533760;
    unsigned short* WtT  = WtH + 131072;
    unsigned short* Ut   = WtT + 131072;           // 10*128*128
    float* hwp  = (float*)(Ut + 163840);           // 8160*12
    float* twp  = hwp + 97920;
    float* tblp = twp + 97920;                     // 256*12

    hipLaunchKernelGGL(convert_k, dim3(1664), dim3(256), 0, stream,
                       head_w, tail_w, U, WtH, WtT, Ut);
    hipLaunchKernelGGL(ht_mfma, dim3(128, 2), dim3(256), 0, stream,
                       state, WtH, WtT, head_b, tail_b, hbuf, tbuf);
    hipLaunchKernelGGL(hU_mfma, dim3(64, 10), dim3(256), 0, stream,
                       hbuf, Ut, hUb);
    hipLaunchKernelGGL(small_k, dim3(778), dim3(256), 0, stream,
                       hbuf, tbuf, wtab, cls_w, cls_b, hwp, twp, tblp);
    hipLaunchKernelGGL(main_mfma, dim3(24, 2, 32), dim3(256), 0, stream,
                       hUb, tbuf, hwp, twp, tblp, out);
}

// Round 3
// 94.161 us; speedup vs baseline: 7.2366x; 1.0308x over previous
//
#include <hip/hip_runtime.h>
#include <hip/hip_bf16.h>

using f32x4 = __attribute__((ext_vector_type(4))) float;
using f32x2 = __attribute__((ext_vector_type(2))) float;
using s16x8 = __attribute__((ext_vector_type(8))) short;
using s16x4 = __attribute__((ext_vector_type(4))) short;

constexpr int S = 255, RTOT = 32 * 255;          // 8160
constexpr int NHW = 8160 * 12;

__device__ inline unsigned short f2bf(float x) {
    __hip_bfloat16 b = __float2bfloat16(x);      // RNE
    return __builtin_bit_cast(unsigned short, b);
}
__device__ inline float bf2f(unsigned short u) {
    unsigned int t = ((unsigned int)u) << 16;
    return __builtin_bit_cast(float, t);
}
__device__ inline f32x4 mfma16(s16x8 a, s16x8 b, f32x4 c) {
    return __builtin_amdgcn_mfma_f32_16x16x32_bf16(a, b, c, 0, 0, 0);
}
// async global->LDS, 16B per lane; LDS dest = wave-uniform base + lane*16.
__device__ inline void gload16(const unsigned short* g, unsigned short* l) {
    __builtin_amdgcn_global_load_lds(
        (const __attribute__((address_space(1))) void*)g,
        (__attribute__((address_space(3))) void*)l, 16, 0, 0);
}

// ---------------------------------------------------------------------------
// K0: weight conversion.
//  WP: [kstep 16][n 256][kc' 8][e 8] bf16, pre-swizzled (kc = kc'^(n&7)) so
//      ht_mfma can global_load_lds it linearly. n<128 = head_w col n, n>=128
//      = tail_w col n-128; cols >=120 zero.
//  Ut: [o][j pad128][i pad128] bf16 for hU_mfma.
// ---------------------------------------------------------------------------
__global__ __launch_bounds__(256) void convert_k(
    const float* __restrict__ head_w, const float* __restrict__ tail_w,
    const float* __restrict__ U,
    unsigned short* __restrict__ WP, unsigned short* __restrict__ Ut)
{
    int gid = blockIdx.x * 256 + threadIdx.x;
    if (gid < 262144) {
        int e = gid & 7, kcp = (gid >> 3) & 7, n = (gid >> 6) & 255, ks = gid >> 14;
        int kc = kcp ^ (n & 7);
        int k = ks * 64 + kc * 8 + e;
        float v;
        if (n < 128) v = (n < 120) ? head_w[k * 120 + n] : 0.f;
        else { int nn = n - 128; v = (nn < 120) ? tail_w[k * 120 + nn] : 0.f; }
        WP[gid] = f2bf(v);
    } else {
        int idx = gid - 262144;
        if (idx < 163840) {
            int o = idx >> 14, rem = idx & 16383;
            int j = rem >> 7, i2 = rem & 127;
            float v = (i2 < 120 && j < 120) ? U[((size_t)o * 120 + i2) * 120 + j] : 0.f;
            Ut[(size_t)o * 16384 + (size_t)j * 128 + i2] = f2bf(v);
        }
    }
}

// ---------------------------------------------------------------------------
// K1: h/t = leaky(state @ W + b), head+tail fused (state read ONCE).
// grid 255 (r-tile 32), 256 thr / 4 waves. K=1024, 16 steps of 64, dbuf.
// W via global_load_lds from pre-swizzled WP; state reg-loaded early (T14),
// converted + ds_write'd into the next buffer after compute.
// ---------------------------------------------------------------------------
__global__ __launch_bounds__(256) void ht_mfma(
    const float* __restrict__ state, const unsigned short* __restrict__ WP,
    const float* __restrict__ head_b, const float* __restrict__ tail_b,
    unsigned short* __restrict__ hbuf, unsigned short* __restrict__ tbuf)
{
    __shared__ unsigned short Ss[2][32 * 64];     //  8 KB: state tile bf16
    __shared__ unsigned short Ws[2][256 * 64];    // 64 KB: both W tiles
    const int r0 = blockIdx.x * 32;
    const int tid = threadIdx.x;
    const int w = tid >> 6, lane = tid & 63;
    const int l16 = lane & 15, kq = lane >> 4;
    const int srow = tid >> 3, skc = tid & 7;
    const float* sp = &state[(size_t)(r0 + srow) * 1024 + skc * 8];

    f32x4 acc[4][2];
    #pragma unroll
    for (int fn = 0; fn < 4; ++fn)
        #pragma unroll
        for (int fr = 0; fr < 2; ++fr) acc[fn][fr] = (f32x4){0.f, 0.f, 0.f, 0.f};

    // prologue: stage iter 0 into buf 0
    #pragma unroll
    for (int j = 0; j < 8; ++j) {
        int off = (w * 8 + j) * 512;
        gload16(WP + off + lane * 8, &Ws[0][off]);
    }
    {
        f32x4 a0 = *(const f32x4*)sp;
        f32x4 a1 = *(const f32x4*)(sp + 4);
        s16x8 pk;
        #pragma unroll
        for (int e = 0; e < 4; ++e) { pk[e] = (short)f2bf(a0[e]); pk[e + 4] = (short)f2bf(a1[e]); }
        *(s16x8*)((char*)&Ss[0][0] + srow * 128 + ((skc * 16) ^ ((srow & 7) << 4))) = pk;
    }
    __syncthreads();

    for (int it = 0; it < 16; ++it) {
        const int cur = it & 1;
        f32x4 a0, a1;
        if (it < 15) {
            #pragma unroll
            for (int j = 0; j < 8; ++j) {
                int off = (w * 8 + j) * 512;
                gload16(WP + (it + 1) * 16384 + off + lane * 8, &Ws[cur ^ 1][off]);
            }
            a0 = *(const f32x4*)(sp + (it + 1) * 64);
            a1 = *(const f32x4*)(sp + (it + 1) * 64 + 4);
        }
        // compute from buf[cur]
        const char* SsB = (const char*)&Ss[cur][0];
        const char* WsB = (const char*)&Ws[cur][0];
        s16x8 bf[2][2];
        #pragma unroll
        for (int fr = 0; fr < 2; ++fr) {
            int rr = fr * 16 + l16;
            #pragma unroll
            for (int ks = 0; ks < 2; ++ks)
                bf[fr][ks] = *(const s16x8*)(SsB + rr * 128 + ((ks * 64 + kq * 16) ^ ((rr & 7) << 4)));
        }
        #pragma unroll
        for (int fn = 0; fn < 4; ++fn) {
            int n = w * 64 + fn * 16 + l16;
            #pragma unroll
            for (int ks = 0; ks < 2; ++ks) {
                s16x8 af = *(const s16x8*)(WsB + n * 128 + ((ks * 64 + kq * 16) ^ ((n & 7) << 4)));
                #pragma unroll
                for (int fr = 0; fr < 2; ++fr)
                    acc[fn][fr] = mfma16(af, bf[fr][ks], acc[fn][fr]);
            }
        }
        if (it < 15) {
            s16x8 pk;
            #pragma unroll
            for (int e = 0; e < 4; ++e) { pk[e] = (short)f2bf(a0[e]); pk[e + 4] = (short)f2bf(a1[e]); }
            *(s16x8*)((char*)&Ss[cur ^ 1][0] + srow * 128 + ((skc * 16) ^ ((srow & 7) << 4))) = pk;
        }
        __syncthreads();
    }

    // epilogue: bias + leaky, split halves to hbuf / tbuf
    #pragma unroll
    for (int fn = 0; fn < 4; ++fn) {
        const int n0 = w * 64 + fn * 16 + kq * 4;
        const int isT = n0 >= 128;
        const int c0 = n0 & 127;
        const float* bp = isT ? tail_b : head_b;
        unsigned short* dst = isT ? tbuf : hbuf;
        #pragma unroll
        for (int fr = 0; fr < 2; ++fr) {
            const int r = r0 + fr * 16 + l16;
            s16x4 pk;
            #pragma unroll
            for (int e = 0; e < 4; ++e) {
                float bv = (c0 + e < 120) ? bp[c0 + e] : 0.f;
                float z = acc[fn][fr][e] + bv;
                z = (z >= 0.f) ? z : 0.01f * z;
                pk[e] = (short)f2bf(z);
            }
            *(s16x4*)&dst[(size_t)r * 128 + c0] = pk;
        }
    }
}

// ---------------------------------------------------------------------------
// K2: hU[r][o][j] = sum_i h[r][i] U[o][i][j].  (unchanged from round 2)
// ---------------------------------------------------------------------------
__global__ __launch_bounds__(256) void hU_mfma(
    const unsigned short* __restrict__ hbuf, const unsigned short* __restrict__ Ut,
    unsigned short* __restrict__ hU)
{
    __shared__ unsigned short Hs[128 * 128];
    __shared__ unsigned short Us[128 * 128];
    const int r0 = blockIdx.x * 128;
    const int o = blockIdx.y;
    const int tid = threadIdx.x;
    const int w = tid >> 6, lane = tid & 63;
    const int l16 = lane & 15, kq = lane >> 4;
    char* HsB = (char*)Hs;
    char* UsB = (char*)Us;

    #pragma unroll
    for (int i = 0; i < 8; ++i) {
        int idx = i * 256 + tid;
        int row = idx >> 4, kc = idx & 15;
        int r = r0 + row;
        s16x8 pk = {0, 0, 0, 0, 0, 0, 0, 0};
        if (r < RTOT) pk = *(const s16x8*)&hbuf[(size_t)r * 128 + kc * 8];
        *(s16x8*)(HsB + row * 256 + ((kc * 16) ^ ((row & 7) << 4))) = pk;
        s16x8 pu = *(const s16x8*)&Ut[(size_t)o * 16384 + (size_t)row * 128 + kc * 8];
        *(s16x8*)(UsB + row * 256 + ((kc * 16) ^ ((row & 7) << 4))) = pu;
    }
    __syncthreads();

    f32x4 acc[2][8];
    #pragma unroll
    for (int a = 0; a < 2; ++a)
        #pragma unroll
        for (int b2 = 0; b2 < 8; ++b2) acc[a][b2] = (f32x4){0.f, 0.f, 0.f, 0.f};

    #pragma unroll
    for (int ks = 0; ks < 4; ++ks) {
        int kb = ks * 64 + kq * 16;
        s16x8 bf[2];
        #pragma unroll
        for (int fr = 0; fr < 2; ++fr) {
            int row = w * 32 + fr * 16 + l16;
            bf[fr] = *(const s16x8*)(HsB + row * 256 + (kb ^ ((row & 7) << 4)));
        }
        #pragma unroll
        for (int fj = 0; fj < 8; ++fj) {
            int j = fj * 16 + l16;
            s16x8 af = *(const s16x8*)(UsB + j * 256 + (kb ^ ((j & 7) << 4)));
            #pragma unroll
            for (int fr = 0; fr < 2; ++fr)
                acc[fr][fj] = mfma16(af, bf[fr], acc[fr][fj]);
        }
    }

    #pragma unroll
    for (int fr = 0; fr < 2; ++fr) {
        int r = r0 + w * 32 + fr * 16 + l16;
        if (r < RTOT) {
            #pragma unroll
            for (int fj = 0; fj < 8; ++fj) {
                int j0 = fj * 16 + kq * 4;
                s16x4 pk;
                #pragma unroll
                for (int e = 0; e < 4; ++e) pk[e] = (short)f2bf(acc[fr][fj][e]);
                *(s16x4*)&hU[((size_t)r * 12 + o) * 128 + j0] = pk;
            }
        }
    }
}

// ---------------------------------------------------------------------------
// K3: hw[r][12], tw[r][12], tbl[256][12] fp32 (pads = 0)  (unchanged)
// ---------------------------------------------------------------------------
__global__ __launch_bounds__(256) void small_k(
    const unsigned short* __restrict__ hbuf, const unsigned short* __restrict__ tbuf,
    const float* __restrict__ wtab, const float* __restrict__ cls_w,
    const float* __restrict__ cls_b,
    float* __restrict__ hwp, float* __restrict__ twp, float* __restrict__ tblp)
{
    const int gid = blockIdx.x * 256 + threadIdx.x;
    if (gid < 2 * NHW) {
        int which = gid >= NHW;
        int rem = which ? gid - NHW : gid;
        int r = rem / 12, o = rem % 12;
        float s = 0.f;
        if (o < 10) {
            const unsigned short* src = (which ? tbuf : hbuf) + (size_t)r * 128;
            const float* wrow = cls_w + o * 262 + which * 121;
            #pragma unroll
            for (int c = 0; c < 15; ++c) {
                s16x8 v = *(const s16x8*)&src[c * 8];
                #pragma unroll
                for (int e = 0; e < 8; ++e)
                    s += bf2f((unsigned short)v[e]) * wrow[c * 8 + e];
            }
            s += wrow[120];                       // "ones" column
            if (!which) s += cls_b[o];
        }
        if (which) twp[rem] = s; else hwp[rem] = s;
    } else {
        int id = gid - 2 * NHW;
        if (id < 256 * 12) {
            int p = id / 12, o = id % 12;
            float s = 0.f;
            if (o < 10) {
                for (int wq = 0; wq < 20; ++wq)
                    s += wtab[p * 20 + wq] * cls_w[o * 262 + 242 + wq];
            }
            tblp[id] = s;
        }
    }
}

// ---------------------------------------------------------------------------
// K4: out = hU[b] @ t[b]^T + hw + tw + tbl.
// grid (8 mgroups, 32 b) = 256 blocks (1/CU), 512 thr / 8 waves (2m x 4y).
// Per block: B (all 256 y, 64 KB) staged once via global_load_lds, B-frags
// hoisted to regs; 3 m-tiles of 128 with double-buffered A prefetch.
// ---------------------------------------------------------------------------
__global__ __launch_bounds__(512) void main_mfma(
    const unsigned short* __restrict__ hU, const unsigned short* __restrict__ tbuf,
    const float* __restrict__ hwp, const float* __restrict__ twp,
    const float* __restrict__ tblp, float* __restrict__ out)
{
    __shared__ unsigned short Bs[256 * 128];      // 64 KB
    __shared__ unsigned short As[2][128 * 128];   // 2 x 32 KB
    const int mg = blockIdx.x, b = blockIdx.y;
    const int tid = threadIdx.x;
    const int w = tid >> 6, lane = tid & 63;
    const int l16 = lane & 15, kq = lane >> 4;
    const int wm = w >> 2, wy = w & 3;
    const size_t hUbase = (size_t)b * 3060 * 128;

    // stage B: t rows b*255 + [0,256), pre-swizzled source, linear LDS
    #pragma unroll
    for (int j = 0; j < 8; ++j) {
        int E = (w * 8 + j) * 512 + lane * 8;
        int row = E >> 7, kcp = (E & 127) >> 3;
        int kc = kcp ^ (row & 7);
        gload16(&tbuf[(size_t)(b * 255 + row) * 128 + kc * 8], &Bs[(w * 8 + j) * 512]);
    }
    // stage A tile 0
    {
        const int m0 = mg * 3 * 128;
        #pragma unroll
        for (int j = 0; j < 4; ++j) {
            int E = (w * 4 + j) * 512 + lane * 8;
            int row = E >> 7, kcp = (E & 127) >> 3;
            int kc = kcp ^ (row & 7);
            gload16(&hU[hUbase + (size_t)(m0 + row) * 128 + kc * 8], &As[0][(w * 4 + j) * 512]);
        }
    }
    __syncthreads();

    // hoist all B fragments into registers (64 VGPR)
    s16x8 bfr[4][4];   // [ks][fy]
    #pragma unroll
    for (int ks = 0; ks < 4; ++ks)
        #pragma unroll
        for (int fy = 0; fy < 4; ++fy) {
            int row = wy * 64 + fy * 16 + l16;
            bfr[ks][fy] = *(const s16x8*)((const char*)Bs + row * 256 +
                           ((ks * 64 + kq * 16) ^ ((row & 7) << 4)));
        }

    for (int i = 0; i < 3; ++i) {
        const int m0 = (mg * 3 + i) * 128;
        if (i < 2) {                                // prefetch next A tile
            const int m0n = (mg * 3 + i + 1) * 128;
            #pragma unroll
            for (int j = 0; j < 4; ++j) {
                int E = (w * 4 + j) * 512 + lane * 8;
                int row = E >> 7, kcp = (E & 127) >> 3;
                int kc = kcp ^ (row & 7);
                gload16(&hU[hUbase + (size_t)(m0n + row) * 128 + kc * 8],
                        &As[(i + 1) & 1][(w * 4 + j) * 512]);
            }
        }
        const char* AsB = (const char*)&As[i & 1][0];
        f32x4 acc[4][4];
        #pragma unroll
        for (int fm = 0; fm < 4; ++fm)
            #pragma unroll
            for (int fy = 0; fy < 4; ++fy) acc[fm][fy] = (f32x4){0.f, 0.f, 0.f, 0.f};

        #pragma unroll
        for (int ks = 0; ks < 4; ++ks) {
            s16x8 af[4];
            #pragma unroll
            for (int fm = 0; fm < 4; ++fm) {
                int row = wm * 64 + fm * 16 + l16;
                af[fm] = *(const s16x8*)(AsB + row * 256 +
                          ((ks * 64 + kq * 16) ^ ((row & 7) << 4)));
            }
            #pragma unroll
            for (int fm = 0; fm < 4; ++fm)
                #pragma unroll
                for (int fy = 0; fy < 4; ++fy)
                    acc[fm][fy] = mfma16(af[fm], bfr[ks][fy], acc[fm][fy]);
        }

        // epilogue for this m-tile
        #pragma unroll
        for (int fm = 0; fm < 4; ++fm) {
            const int ml = m0 + wm * 64 + fm * 16 + kq * 4;
            if (ml < 3060) {
                const int x = ml / 12, o0 = ml % 12;      // o0 in {0,4,8}
                const int rx = b * 255 + x;
                f32x4 hv = *(const f32x4*)&hwp[(size_t)rx * 12 + o0];
                #pragma unroll
                for (int fy = 0; fy < 4; ++fy) {
                    const int y = wy * 64 + fy * 16 + l16;
                    if (y < 255) {
                        const int ry = b * 255 + y;
                        f32x4 tv = *(const f32x4*)&twp[(size_t)ry * 12 + o0];
                        int p = y - x + 1; if (p < 0) p = 0;
                        f32x4 wv = *(const f32x4*)&tblp[p * 12 + o0];
                        float* op = &out[((size_t)rx * 255 + y) * 10 + o0];
                        if (o0 < 8) {
                            float v[4];
                            #pragma unroll
                            for (int e = 0; e < 4; ++e)
                                v[e] = acc[fm][fy][e] + hv[e] + tv[e] + wv[e];
                            __builtin_memcpy(op, v, 16);
                        } else {
                            float v[2];
                            v[0] = acc[fm][fy][0] + hv[0] + tv[0] + wv[0];
                            v[1] = acc[fm][fy][1] + hv[1] + tv[1] + wv[1];
                            __builtin_memcpy(op, v, 8);
                        }
                    }
                }
            }
        }
        __syncthreads();   // drains prefetch (vmcnt 0) + protects As buffer swap
    }
}

// ---------------------------------------------------------------------------
extern "C" void kernel_launch(void* const* d_in, const int* in_sizes, int n_in,
                              void* d_out, int out_size, void* d_ws, size_t ws_size,
                              hipStream_t stream)
{
    (void)in_sizes; (void)n_in; (void)out_size; (void)ws_size;
    const float* state  = (const float*)d_in[0];
    const float* head_w = (const float*)d_in[1];
    const float* head_b = (const float*)d_in[2];
    const float* tail_w = (const float*)d_in[3];
    const float* tail_b = (const float*)d_in[4];
    const float* U      = (const float*)d_in[5];
    const float* wtab   = (const float*)d_in[6];
    const float* cls_w  = (const float*)d_in[7];
    const float* cls_b  = (const float*)d_in[8];
    float* out = (float*)d_out;

    unsigned short* u16 = (unsigned short*)d_ws;
    unsigned short* hbuf = u16;                    // 8160*128
    unsigned short* tbuf = hbuf + 1044480;
    unsigned short* hUb  = tbuf + 1044480;         // 8160*12*128
    unsigned short* WP   = hUb + 12533760;         // 16*256*64 = 262144
    unsigned short* Ut   = WP + 262144;            // 10*128*128
    float* hwp  = (float*)(Ut + 163840);           // 8160*12
    float* twp  = hwp + 97920;
    float* tblp = twp + 97920;                     // 256*12

    hipLaunchKernelGGL(convert_k, dim3(1664), dim3(256), 0, stream,
                       head_w, tail_w, U, WP, Ut);
    hipLaunchKernelGGL(ht_mfma, dim3(255), dim3(256), 0, stream,
                       state, WP, head_b, tail_b, hbuf, tbuf);
    hipLaunchKernelGGL(hU_mfma, dim3(64, 10), dim3(256), 0, stream,
                       hbuf, Ut, hUb);
    hipLaunchKernelGGL(small_k, dim3(778), dim3(256), 0, stream,
                       hbuf, tbuf, wtab, cls_w, cls_b, hwp, twp, tblp);
    hipLaunchKernelGGL(main_mfma, dim3(8, 32), dim3(512), 0, stream,
                       hUb, tbuf, hwp, twp, tblp, out);
}

// Round 4
// 89.500 us; speedup vs baseline: 7.6135x; 1.0521x over previous
//
#include <hip/hip_runtime.h>
#include <hip/hip_bf16.h>

using f32x4 = __attribute__((ext_vector_type(4))) float;
using s16x8 = __attribute__((ext_vector_type(8))) short;
using s16x4 = __attribute__((ext_vector_type(4))) short;

constexpr int S = 255, RTOT = 32 * 255;          // 8160

__device__ inline unsigned short f2bf(float x) {
    __hip_bfloat16 b = __float2bfloat16(x);      // RNE
    return __builtin_bit_cast(unsigned short, b);
}
__device__ inline float bf2f(unsigned short u) {
    unsigned int t = ((unsigned int)u) << 16;
    return __builtin_bit_cast(float, t);
}
__device__ inline f32x4 mfma16(s16x8 a, s16x8 b, f32x4 c) {
    return __builtin_amdgcn_mfma_f32_16x16x32_bf16(a, b, c, 0, 0, 0);
}
// async global->LDS, 16B per lane; LDS dest = wave-uniform base + lane*16.
__device__ inline void gload16(const unsigned short* g, unsigned short* l) {
    __builtin_amdgcn_global_load_lds(
        (const __attribute__((address_space(1))) void*)g,
        (__attribute__((address_space(3))) void*)l, 16, 0, 0);
}

// Pre-swizzle convention (G21): for every staged [rows][128]-bf16 buffer,
// 16B-chunk c of row r is stored in global at chunk slot (c ^ (key&7)),
// where key == the reader's tile-local row (tile bases are ≡0 mod 8 rows).
// Readers then global_load_lds LINEARLY and ds_read with the same XOR.

// ---------------------------------------------------------------------------
// K0: weight conversion.
//  WP: [kstep 16][n 256][kc' 8][e 8] bf16 pre-swizzled for ht (unchanged).
//  Ut: [o][j 128][i 128] bf16, pre-swizzled with key j&7 (i-chunks permuted).
//  tblp[256][12]: width-table dot (only o<10 written).
// ---------------------------------------------------------------------------
__global__ __launch_bounds__(256) void convert_k(
    const float* __restrict__ head_w, const float* __restrict__ tail_w,
    const float* __restrict__ U, const float* __restrict__ wtab,
    const float* __restrict__ cls_w,
    unsigned short* __restrict__ WP, unsigned short* __restrict__ Ut,
    float* __restrict__ tblp)
{
    int gid = blockIdx.x * 256 + threadIdx.x;
    if (gid < 262144) {
        int e = gid & 7, kcp = (gid >> 3) & 7, n = (gid >> 6) & 255, ks = gid >> 14;
        int kc = kcp ^ (n & 7);
        int k = ks * 64 + kc * 8 + e;
        float v;
        if (n < 128) v = (n < 120) ? head_w[k * 120 + n] : 0.f;
        else { int nn = n - 128; v = (nn < 120) ? tail_w[k * 120 + nn] : 0.f; }
        WP[gid] = f2bf(v);
    } else if (gid < 262144 + 163840) {
        int idx = gid - 262144;
        int j = idx & 127, i2 = (idx >> 7) & 127, o = idx >> 14;   // j fastest: coalesced U read
        float v = (i2 < 120 && j < 120) ? U[((size_t)o * 120 + i2) * 120 + j] : 0.f;
        int ph = (((i2 >> 3) ^ (j & 7)) << 3) | (i2 & 7);
        Ut[(size_t)o * 16384 + (size_t)j * 128 + ph] = f2bf(v);
    } else {
        int id = gid - 262144 - 163840;
        if (id < 2560) {
            int p = id / 10, o = id - (id / 10) * 10;
            float s = 0.f;
            #pragma unroll
            for (int wq = 0; wq < 20; ++wq)
                s += wtab[p * 20 + wq] * cls_w[o * 262 + 242 + wq];
            tblp[p * 12 + o] = s;
        }
    }
}

// ---------------------------------------------------------------------------
// K1: h/t = leaky(state @ W + b), head+tail fused; ALSO computes hw/tw
// (the cls_w dot) from the finished tile via LDS (small_k fused away).
// grid 255 (r-tile 32), 256 thr / 4 waves. K=1024, 16 steps of 64, dbuf.
// Outputs hbuf [8160][128] (key r&7) and tbuf [32][256][128] (key x&7),
// both pre-swizzled.
// ---------------------------------------------------------------------------
__global__ __launch_bounds__(256) void ht_mfma(
    const float* __restrict__ state, const unsigned short* __restrict__ WP,
    const float* __restrict__ head_b, const float* __restrict__ tail_b,
    const float* __restrict__ cls_w, const float* __restrict__ cls_b,
    unsigned short* __restrict__ hbuf, unsigned short* __restrict__ tbuf,
    float* __restrict__ hwp, float* __restrict__ twp)
{
    __shared__ unsigned short Ss[2][32 * 64];     //  8 KB: state tile bf16
    __shared__ unsigned short Ws[2][256 * 64];    // 64 KB: both W tiles
    const int r0 = blockIdx.x * 32;
    const int tid = threadIdx.x;
    const int w = tid >> 6, lane = tid & 63;
    const int l16 = lane & 15, kq = lane >> 4;
    const int srow = tid >> 3, skc = tid & 7;
    const float* sp = &state[(size_t)(r0 + srow) * 1024 + skc * 8];

    f32x4 acc[4][2];
    #pragma unroll
    for (int fn = 0; fn < 4; ++fn)
        #pragma unroll
        for (int fr = 0; fr < 2; ++fr) acc[fn][fr] = (f32x4){0.f, 0.f, 0.f, 0.f};

    // prologue: stage iter 0 into buf 0
    #pragma unroll
    for (int j = 0; j < 8; ++j) {
        int off = (w * 8 + j) * 512;
        gload16(WP + off + lane * 8, &Ws[0][off]);
    }
    {
        f32x4 a0 = *(const f32x4*)sp;
        f32x4 a1 = *(const f32x4*)(sp + 4);
        s16x8 pk;
        #pragma unroll
        for (int e = 0; e < 4; ++e) { pk[e] = (short)f2bf(a0[e]); pk[e + 4] = (short)f2bf(a1[e]); }
        *(s16x8*)((char*)&Ss[0][0] + srow * 128 + ((skc * 16) ^ ((srow & 7) << 4))) = pk;
    }
    __syncthreads();

    for (int it = 0; it < 16; ++it) {
        const int cur = it & 1;
        f32x4 a0, a1;
        if (it < 15) {
            #pragma unroll
            for (int j = 0; j < 8; ++j) {
                int off = (w * 8 + j) * 512;
                gload16(WP + (it + 1) * 16384 + off + lane * 8, &Ws[cur ^ 1][off]);
            }
            a0 = *(const f32x4*)(sp + (it + 1) * 64);
            a1 = *(const f32x4*)(sp + (it + 1) * 64 + 4);
        }
        const char* SsB = (const char*)&Ss[cur][0];
        const char* WsB = (const char*)&Ws[cur][0];
        s16x8 bf[2][2];
        #pragma unroll
        for (int fr = 0; fr < 2; ++fr) {
            int rr = fr * 16 + l16;
            #pragma unroll
            for (int ks = 0; ks < 2; ++ks)
                bf[fr][ks] = *(const s16x8*)(SsB + rr * 128 + ((ks * 64 + kq * 16) ^ ((rr & 7) << 4)));
        }
        #pragma unroll
        for (int fn = 0; fn < 4; ++fn) {
            int n = w * 64 + fn * 16 + l16;
            #pragma unroll
            for (int ks = 0; ks < 2; ++ks) {
                s16x8 af = *(const s16x8*)(WsB + n * 128 + ((ks * 64 + kq * 16) ^ ((n & 7) << 4)));
                #pragma unroll
                for (int fr = 0; fr < 2; ++fr)
                    acc[fn][fr] = mfma16(af, bf[fr][ks], acc[fn][fr]);
            }
        }
        if (it < 15) {
            s16x8 pk;
            #pragma unroll
            for (int e = 0; e < 4; ++e) { pk[e] = (short)f2bf(a0[e]); pk[e + 4] = (short)f2bf(a1[e]); }
            *(s16x8*)((char*)&Ss[cur ^ 1][0] + srow * 128 + ((skc * 16) ^ ((srow & 7) << 4))) = pk;
        }
        __syncthreads();
    }

    // ---- epilogue: bias + leaky, pre-swizzled global stores + LDS tiles ----
    unsigned short* Hl = &Ws[0][0];                   // [32][128] linear
    unsigned short* Tl = &Ws[1][0];                   // [32][128] linear
    #pragma unroll
    for (int fn = 0; fn < 4; ++fn) {
        const int n0 = w * 64 + fn * 16 + kq * 4;     // wave-uniform isT
        const int isT = n0 >= 128;
        const int c0 = n0 & 127;
        const int g = c0 >> 3, sub = (kq & 1) * 4;
        const float* bp = isT ? tail_b : head_b;
        #pragma unroll
        for (int fr = 0; fr < 2; ++fr) {
            const int rloc = fr * 16 + l16;
            const int r = r0 + rloc;
            s16x4 pk;
            #pragma unroll
            for (int e = 0; e < 4; ++e) {
                float bv = (c0 + e < 120) ? bp[c0 + e] : 0.f;
                float z = acc[fn][fr][e] + bv;
                z = (z >= 0.f) ? z : 0.01f * z;
                pk[e] = (short)f2bf(z);
            }
            if (isT) {
                int bq = r / 255, x = r - bq * 255;
                *(s16x4*)&tbuf[((size_t)bq * 256 + x) * 128 + ((g ^ (x & 7)) << 3) + sub] = pk;
                *(s16x4*)&Tl[rloc * 128 + c0] = pk;
            } else {
                *(s16x4*)&hbuf[(size_t)r * 128 + ((g ^ (r & 7)) << 3) + sub] = pk;
                *(s16x4*)&Hl[rloc * 128 + c0] = pk;
            }
        }
    }
    __syncthreads();

    // ---- fused small_k: hw/tw dots from LDS tiles ----
    float* Wl = (float*)&Ws[0][4096];     // 2430 f32: [which][o][121] + cls_b[10]
    for (int idx = tid; idx < 2430; idx += 256) {
        if (idx < 2420) {
            int which = idx / 1210, rem = idx - which * 1210;
            int o = rem / 121, i = rem - o * 121;
            Wl[idx] = cls_w[o * 262 + which * 121 + i];
        } else Wl[idx] = cls_b[idx - 2420];
    }
    __syncthreads();
    for (int d = tid; d < 640; d += 256) {
        int which = d / 320, rem = d - which * 320;
        int rr = rem / 10, o = rem - rr * 10;
        const unsigned short* row = (which ? Tl : Hl) + rr * 128;
        const float* wp2 = &Wl[which * 1210 + o * 121];
        float s = 0.f;
        #pragma unroll
        for (int c = 0; c < 15; ++c) {
            s16x8 v = *(const s16x8*)&row[c * 8];
            #pragma unroll
            for (int e = 0; e < 8; ++e)
                s += bf2f((unsigned short)v[e]) * wp2[c * 8 + e];
        }
        s += wp2[120];                                 // "ones" column
        int gr = r0 + rr;
        if (!which) hwp[(size_t)gr * 12 + o] = s + Wl[2420 + o];
        else        twp[(size_t)gr * 12 + o] = s;
    }
}

// ---------------------------------------------------------------------------
// K2: hU[b][m=x*12+o][j] = sum_i h[r][i] U[o][i][j]; output pre-swizzled
// (key m&7), rows for o>=10 / m>=3060 left unwritten (discarded downstream).
// grid (64 r-blocks of 128, 10 o). Staging via linear global_load_lds.
// ---------------------------------------------------------------------------
__global__ __launch_bounds__(256) void hU_mfma(
    const unsigned short* __restrict__ hbuf, const unsigned short* __restrict__ Ut,
    unsigned short* __restrict__ hU)
{
    __shared__ unsigned short Hs[128 * 128];
    __shared__ unsigned short Us[128 * 128];
    const int r0 = blockIdx.x * 128;
    const int o = blockIdx.y;
    const int tid = threadIdx.x;
    const int w = tid >> 6, lane = tid & 63;
    const int l16 = lane & 15, kq = lane >> 4;
    const char* HsB = (const char*)Hs;
    const char* UsB = (const char*)Us;

    #pragma unroll
    for (int j = 0; j < 8; ++j) {
        int off = (w * 8 + j) * 512;
        gload16(&hbuf[(size_t)r0 * 128 + off + lane * 8], &Hs[off]);
        gload16(&Ut[(size_t)o * 16384 + off + lane * 8], &Us[off]);
    }
    __syncthreads();

    f32x4 acc[2][8];
    #pragma unroll
    for (int a = 0; a < 2; ++a)
        #pragma unroll
        for (int b2 = 0; b2 < 8; ++b2) acc[a][b2] = (f32x4){0.f, 0.f, 0.f, 0.f};

    #pragma unroll
    for (int ks = 0; ks < 4; ++ks) {
        int kb = ks * 64 + kq * 16;
        s16x8 bf[2];
        #pragma unroll
        for (int fr = 0; fr < 2; ++fr) {
            int row = w * 32 + fr * 16 + l16;
            bf[fr] = *(const s16x8*)(HsB + row * 256 + (kb ^ ((row & 7) << 4)));
        }
        #pragma unroll
        for (int fj = 0; fj < 8; ++fj) {
            int j = fj * 16 + l16;
            s16x8 af = *(const s16x8*)(UsB + j * 256 + (kb ^ ((j & 7) << 4)));
            #pragma unroll
            for (int fr = 0; fr < 2; ++fr)
                acc[fr][fj] = mfma16(af, bf[fr], acc[fr][fj]);
        }
    }

    #pragma unroll
    for (int fr = 0; fr < 2; ++fr) {
        int r = r0 + w * 32 + fr * 16 + l16;
        if (r < RTOT) {
            int bq = r / 255, x = r - bq * 255;
            int m = x * 12 + o;
            size_t rowbase = ((size_t)bq * 3072 + m) * 128;
            int key = m & 7, sub = (kq & 1) * 4;
            #pragma unroll
            for (int fj = 0; fj < 8; ++fj) {
                int g = fj * 2 + (kq >> 1);
                s16x4 pk;
                #pragma unroll
                for (int e = 0; e < 4; ++e) pk[e] = (short)f2bf(acc[fr][fj][e]);
                *(s16x4*)&hU[rowbase + ((g ^ key) << 3) + sub] = pk;
            }
        }
    }
}

// ---------------------------------------------------------------------------
// K4: out = hU[b] @ t[b]^T + hw + tw + tbl.
// grid (8 mgroups, 32 b), 512 thr / 8 waves (2m x 4y). B staged once
// (linear gload), B-frags hoisted; 3 m-tiles with dbuf A prefetch;
// stores issued AFTER the barrier so they drain under the next tile's MFMA.
// ---------------------------------------------------------------------------
__global__ __launch_bounds__(512) void main_mfma(
    const unsigned short* __restrict__ hU, const unsigned short* __restrict__ tbuf,
    const float* __restrict__ hwp, const float* __restrict__ twp,
    const float* __restrict__ tblp, float* __restrict__ out)
{
    __shared__ unsigned short Bs[256 * 128];      // 64 KB
    __shared__ unsigned short As[2][128 * 128];   // 2 x 32 KB
    const int mg = blockIdx.x, b = blockIdx.y;
    const int tid = threadIdx.x;
    const int w = tid >> 6, lane = tid & 63;
    const int l16 = lane & 15, kq = lane >> 4;
    const int wm = w >> 2, wy = w & 3;
    const size_t hUbase = (size_t)b * 3072 * 128;
    const size_t tbase = (size_t)b * 256 * 128;

    #pragma unroll
    for (int j = 0; j < 8; ++j) {
        int off = (w * 8 + j) * 512;
        gload16(&tbuf[tbase + off + lane * 8], &Bs[off]);
    }
    {
        const size_t a0 = hUbase + (size_t)(mg * 3 * 128) * 128;
        #pragma unroll
        for (int j = 0; j < 4; ++j) {
            int off = (w * 4 + j) * 512;
            gload16(&hU[a0 + off + lane * 8], &As[0][off]);
        }
    }
    __syncthreads();

    // hoist all B fragments into registers
    s16x8 bfr[4][4];   // [ks][fy]
    #pragma unroll
    for (int ks = 0; ks < 4; ++ks)
        #pragma unroll
        for (int fy = 0; fy < 4; ++fy) {
            int row = wy * 64 + fy * 16 + l16;
            bfr[ks][fy] = *(const s16x8*)((const char*)Bs + row * 256 +
                           ((ks * 64 + kq * 16) ^ ((row & 7) << 4)));
        }

    for (int i = 0; i < 3; ++i) {
        const int m0 = (mg * 3 + i) * 128;
        if (i < 2) {                                // prefetch next A tile
            const size_t an = hUbase + (size_t)(m0 + 128) * 128;
            #pragma unroll
            for (int j = 0; j < 4; ++j) {
                int off = (w * 4 + j) * 512;
                gload16(&hU[an + off + lane * 8], &As[(i + 1) & 1][off]);
            }
        }
        const char* AsB = (const char*)&As[i & 1][0];
        f32x4 acc[4][4];
        #pragma unroll
        for (int fm = 0; fm < 4; ++fm)
            #pragma unroll
            for (int fy = 0; fy < 4; ++fy) acc[fm][fy] = (f32x4){0.f, 0.f, 0.f, 0.f};

        #pragma unroll
        for (int ks = 0; ks < 4; ++ks) {
            s16x8 af[4];
            #pragma unroll
            for (int fm = 0; fm < 4; ++fm) {
                int row = wm * 64 + fm * 16 + l16;
                af[fm] = *(const s16x8*)(AsB + row * 256 +
                          ((ks * 64 + kq * 16) ^ ((row & 7) << 4)));
            }
            #pragma unroll
            for (int fm = 0; fm < 4; ++fm)
                #pragma unroll
                for (int fy = 0; fy < 4; ++fy)
                    acc[fm][fy] = mfma16(af[fm], bfr[ks][fy], acc[fm][fy]);
        }

        __syncthreads();   // waits prefetch; stores below overlap next MFMA

        #pragma unroll
        for (int fm = 0; fm < 4; ++fm) {
            const int ml = m0 + wm * 64 + fm * 16 + kq * 4;
            if (ml < 3060) {
                const int x = ml / 12, o0 = ml % 12;      // o0 in {0,4,8}
                const int rx = b * 255 + x;
                f32x4 hv = *(const f32x4*)&hwp[(size_t)rx * 12 + o0];
                #pragma unroll
                for (int fy = 0; fy < 4; ++fy) {
                    const int y = wy * 64 + fy * 16 + l16;
                    if (y < 255) {
                        const int ry = b * 255 + y;
                        f32x4 tv = *(const f32x4*)&twp[(size_t)ry * 12 + o0];
                        int p = y - x + 1; if (p < 0) p = 0;
                        f32x4 wv = *(const f32x4*)&tblp[p * 12 + o0];
                        float* op = &out[((size_t)rx * 255 + y) * 10 + o0];
                        if (o0 < 8) {
                            float v[4];
                            #pragma unroll
                            for (int e = 0; e < 4; ++e)
                                v[e] = acc[fm][fy][e] + hv[e] + tv[e] + wv[e];
                            __builtin_memcpy(op, v, 16);
                        } else {
                            float v[2];
                            v[0] = acc[fm][fy][0] + hv[0] + tv[0] + wv[0];
                            v[1] = acc[fm][fy][1] + hv[1] + tv[1] + wv[1];
                            __builtin_memcpy(op, v, 8);
                        }
                    }
                }
            }
        }
    }
}

// ---------------------------------------------------------------------------
extern "C" void kernel_launch(void* const* d_in, const int* in_sizes, int n_in,
                              void* d_out, int out_size, void* d_ws, size_t ws_size,
                              hipStream_t stream)
{
    (void)in_sizes; (void)n_in; (void)out_size; (void)ws_size;
    const float* state  = (const float*)d_in[0];
    const float* head_w = (const float*)d_in[1];
    const float* head_b = (const float*)d_in[2];
    const float* tail_w = (const float*)d_in[3];
    const float* tail_b = (const float*)d_in[4];
    const float* U      = (const float*)d_in[5];
    const float* wtab   = (const float*)d_in[6];
    const float* cls_w  = (const float*)d_in[7];
    const float* cls_b  = (const float*)d_in[8];
    float* out = (float*)d_out;

    unsigned short* u16 = (unsigned short*)d_ws;
    unsigned short* hbuf = u16;                    // 8160*128      = 1044480
    unsigned short* tbuf = hbuf + 1044480;         // 32*256*128    = 1048576
    unsigned short* hUb  = tbuf + 1048576;         // 32*3072*128   = 12582912
    unsigned short* WP   = hUb + 12582912;         // 16*256*64     = 262144
    unsigned short* Ut   = WP + 262144;            // 10*128*128    = 163840
    float* hwp  = (float*)(Ut + 163840);           // 8160*12
    float* twp  = hwp + 97920;
    float* tblp = twp + 97920;                     // 256*12

    hipLaunchKernelGGL(convert_k, dim3(1674), dim3(256), 0, stream,
                       head_w, tail_w, U, wtab, cls_w, WP, Ut, tblp);
    hipLaunchKernelGGL(ht_mfma, dim3(255), dim3(256), 0, stream,
                       state, WP, head_b, tail_b, cls_w, cls_b,
                       hbuf, tbuf, hwp, twp);
    hipLaunchKernelGGL(hU_mfma, dim3(64, 10), dim3(256), 0, stream,
                       hbuf, Ut, hUb);
    hipLaunchKernelGGL(main_mfma, dim3(8, 32), dim3(512), 0, stream,
                       hUb, tbuf, hwp, twp, tblp, out);
}

// Round 5
// 87.051 us; speedup vs baseline: 7.8277x; 1.0281x over previous
//
#include <hip/hip_runtime.h>
#include <hip/hip_bf16.h>

using f32x4 = __attribute__((ext_vector_type(4))) float;
using s16x8 = __attribute__((ext_vector_type(8))) short;
using s16x4 = __attribute__((ext_vector_type(4))) short;

constexpr int RTOT = 32 * 255;          // 8160

__device__ inline unsigned short f2bf(float x) {
    __hip_bfloat16 b = __float2bfloat16(x);      // RNE
    return __builtin_bit_cast(unsigned short, b);
}
__device__ inline float bf2f(unsigned short u) {
    unsigned int t = ((unsigned int)u) << 16;
    return __builtin_bit_cast(float, t);
}
__device__ inline f32x4 mfma16(s16x8 a, s16x8 b, f32x4 c) {
    return __builtin_amdgcn_mfma_f32_16x16x32_bf16(a, b, c, 0, 0, 0);
}
// async global->LDS, 16B per lane; LDS dest = wave-uniform base + lane*16.
__device__ inline void gload16(const unsigned short* g, unsigned short* l) {
    __builtin_amdgcn_global_load_lds(
        (const __attribute__((address_space(1))) void*)g,
        (__attribute__((address_space(3))) void*)l, 16, 0, 0);
}

// Pre-swizzle convention (G21): for every staged [rows][128]-bf16 buffer,
// 16B-chunk c of row r is stored in global at chunk slot (c ^ (key&7)),
// key == reader's tile-local row (tile bases ≡0 mod 8 rows). Readers
// global_load_lds LINEARLY and ds_read with the same XOR.

// ---------------------------------------------------------------------------
// K0: weight conversion.
//  WP: [kstep 16][n 256][kc' 8][e 8] bf16 pre-swizzled for ht.
//  Ut: [o][j 128][i 128] bf16 PLAIN (read as A-frags directly from L2).
//  tblp[256][12]: width-table dot (only o<10 written).
// ---------------------------------------------------------------------------
__global__ __launch_bounds__(256) void convert_k(
    const float* __restrict__ head_w, const float* __restrict__ tail_w,
    const float* __restrict__ U, const float* __restrict__ wtab,
    const float* __restrict__ cls_w,
    unsigned short* __restrict__ WP, unsigned short* __restrict__ Ut,
    float* __restrict__ tblp)
{
    int gid = blockIdx.x * 256 + threadIdx.x;
    if (gid < 262144) {
        int e = gid & 7, kcp = (gid >> 3) & 7, n = (gid >> 6) & 255, ks = gid >> 14;
        int kc = kcp ^ (n & 7);
        int k = ks * 64 + kc * 8 + e;
        float v;
        if (n < 128) v = (n < 120) ? head_w[k * 120 + n] : 0.f;
        else { int nn = n - 128; v = (nn < 120) ? tail_w[k * 120 + nn] : 0.f; }
        WP[gid] = f2bf(v);
    } else if (gid < 262144 + 163840) {
        int idx = gid - 262144;
        int j = idx & 127, i2 = (idx >> 7) & 127, o = idx >> 14;  // j fastest: coalesced U read
        float v = (i2 < 120 && j < 120) ? U[((size_t)o * 120 + i2) * 120 + j] : 0.f;
        Ut[(size_t)o * 16384 + (size_t)j * 128 + i2] = f2bf(v);
    } else {
        int id = gid - 262144 - 163840;
        if (id < 2560) {
            int p = id / 10, o = id - (id / 10) * 10;
            float s = 0.f;
            #pragma unroll
            for (int wq = 0; wq < 20; ++wq)
                s += wtab[p * 20 + wq] * cls_w[o * 262 + 242 + wq];
            tblp[p * 12 + o] = s;
        }
    }
}

// ---------------------------------------------------------------------------
// K1: h/t = leaky(state @ W + b), head+tail fused; then IN-KERNEL:
//   (a) hUb[m=x*12+o][j] = sum_i h[x][i] U[o][i][j]   (hU kernel fused away)
//   (b) hw/tw cls_w dots                               (small_k fused away)
// grid 255 (r-tile 32), 256 thr / 4 waves. K=1024, 16 steps of 64, dbuf.
// Outputs tbuf [32][256][128] (key x&7) and hUb [32][3072][128] (key m&7),
// both pre-swizzled for downstream global_load_lds.
// ---------------------------------------------------------------------------
__global__ __launch_bounds__(256) void ht_mfma(
    const float* __restrict__ state, const unsigned short* __restrict__ WP,
    const unsigned short* __restrict__ Ut,
    const float* __restrict__ head_b, const float* __restrict__ tail_b,
    const float* __restrict__ cls_w, const float* __restrict__ cls_b,
    unsigned short* __restrict__ tbuf, unsigned short* __restrict__ hUb,
    float* __restrict__ hwp, float* __restrict__ twp)
{
    __shared__ unsigned short Ss[2][32 * 64];     //  8 KB: state tile bf16
    __shared__ unsigned short Ws[2][256 * 64];    // 64 KB: both W tiles
    const int r0 = blockIdx.x * 32;
    const int tid = threadIdx.x;
    const int w = tid >> 6, lane = tid & 63;
    const int l16 = lane & 15, kq = lane >> 4;
    const int srow = tid >> 3, skc = tid & 7;
    const float* sp = &state[(size_t)(r0 + srow) * 1024 + skc * 8];

    f32x4 acc[4][2];
    #pragma unroll
    for (int fn = 0; fn < 4; ++fn)
        #pragma unroll
        for (int fr = 0; fr < 2; ++fr) acc[fn][fr] = (f32x4){0.f, 0.f, 0.f, 0.f};

    // prologue: stage iter 0 into buf 0
    #pragma unroll
    for (int j = 0; j < 8; ++j) {
        int off = (w * 8 + j) * 512;
        gload16(WP + off + lane * 8, &Ws[0][off]);
    }
    {
        f32x4 a0 = *(const f32x4*)sp;
        f32x4 a1 = *(const f32x4*)(sp + 4);
        s16x8 pk;
        #pragma unroll
        for (int e = 0; e < 4; ++e) { pk[e] = (short)f2bf(a0[e]); pk[e + 4] = (short)f2bf(a1[e]); }
        *(s16x8*)((char*)&Ss[0][0] + srow * 128 + ((skc * 16) ^ ((srow & 7) << 4))) = pk;
    }
    __syncthreads();

    for (int it = 0; it < 16; ++it) {
        const int cur = it & 1;
        f32x4 a0, a1;
        if (it < 15) {
            #pragma unroll
            for (int j = 0; j < 8; ++j) {
                int off = (w * 8 + j) * 512;
                gload16(WP + (it + 1) * 16384 + off + lane * 8, &Ws[cur ^ 1][off]);
            }
            a0 = *(const f32x4*)(sp + (it + 1) * 64);
            a1 = *(const f32x4*)(sp + (it + 1) * 64 + 4);
        }
        const char* SsB = (const char*)&Ss[cur][0];
        const char* WsB = (const char*)&Ws[cur][0];
        s16x8 bf[2][2];
        #pragma unroll
        for (int fr = 0; fr < 2; ++fr) {
            int rr = fr * 16 + l16;
            #pragma unroll
            for (int ks = 0; ks < 2; ++ks)
                bf[fr][ks] = *(const s16x8*)(SsB + rr * 128 + ((ks * 64 + kq * 16) ^ ((rr & 7) << 4)));
        }
        #pragma unroll
        for (int fn = 0; fn < 4; ++fn) {
            int n = w * 64 + fn * 16 + l16;
            #pragma unroll
            for (int ks = 0; ks < 2; ++ks) {
                s16x8 af = *(const s16x8*)(WsB + n * 128 + ((ks * 64 + kq * 16) ^ ((n & 7) << 4)));
                #pragma unroll
                for (int fr = 0; fr < 2; ++fr)
                    acc[fn][fr] = mfma16(af, bf[fr][ks], acc[fn][fr]);
            }
        }
        if (it < 15) {
            s16x8 pk;
            #pragma unroll
            for (int e = 0; e < 4; ++e) { pk[e] = (short)f2bf(a0[e]); pk[e + 4] = (short)f2bf(a1[e]); }
            *(s16x8*)((char*)&Ss[cur ^ 1][0] + srow * 128 + ((skc * 16) ^ ((srow & 7) << 4))) = pk;
        }
        __syncthreads();
    }

    // ---- epilogue: bias + leaky -> swizzled LDS tiles (+ tbuf global) ----
    unsigned short* Hl = &Ws[0][0];                   // [32][128] key r&7
    unsigned short* Tl = &Ws[1][0];                   // [32][128] key r&7
    #pragma unroll
    for (int fn = 0; fn < 4; ++fn) {
        const int n0 = w * 64 + fn * 16 + kq * 4;     // wave-uniform isT
        const int isT = n0 >= 128;
        const int c0 = n0 & 127;
        const int g = c0 >> 3, sub = c0 & 7;          // sub = (kq&1)*4
        const float* bp = isT ? tail_b : head_b;
        unsigned short* dstl = isT ? Tl : Hl;
        #pragma unroll
        for (int fr = 0; fr < 2; ++fr) {
            const int rloc = fr * 16 + l16;
            const int r = r0 + rloc;
            s16x4 pk;
            #pragma unroll
            for (int e = 0; e < 4; ++e) {
                float bv = (c0 + e < 120) ? bp[c0 + e] : 0.f;
                float z = acc[fn][fr][e] + bv;
                z = (z >= 0.f) ? z : 0.01f * z;
                pk[e] = (short)f2bf(z);
            }
            *(s16x4*)&dstl[rloc * 128 + ((g ^ (rloc & 7)) << 3) + sub] = pk;
            if (isT) {
                int bq = r / 255, x = r - bq * 255;
                *(s16x4*)&tbuf[((size_t)bq * 256 + x) * 128 + ((g ^ (x & 7)) << 3) + sub] = pk;
            }
        }
    }
    __syncthreads();

    // stage cls_w slices for the hw/tw dots
    float* Wl = (float*)&Ws[0][4096];     // 2430 f32: [which][o][121] + cls_b[10]
    for (int idx = tid; idx < 2430; idx += 256) {
        if (idx < 2420) {
            int which = idx / 1210, rem = idx - which * 1210;
            int o = rem / 121, i = rem - o * 121;
            Wl[idx] = cls_w[o * 262 + which * 121 + i];
        } else Wl[idx] = cls_b[idx - 2420];
    }
    __syncthreads();

    // ---- fused hU: D[j,r] = Ut[o] . h^T, straight to pre-swizzled hUb ----
    {
        s16x8 bh[2][4];   // h B-frags [rf][ks]
        #pragma unroll
        for (int rf = 0; rf < 2; ++rf) {
            int rr = rf * 16 + l16;
            #pragma unroll
            for (int ks = 0; ks < 4; ++ks)
                bh[rf][ks] = *(const s16x8*)((const char*)Hl + rr * 256 +
                              ((ks * 64 + kq * 16) ^ ((rr & 7) << 4)));
        }
        size_t rbase[2]; int x4[2];
        #pragma unroll
        for (int rf = 0; rf < 2; ++rf) {
            int gr = r0 + rf * 16 + l16;
            int bq = gr / 255, x = gr - bq * 255;
            rbase[rf] = ((size_t)bq * 3072 + x * 12) * 128;
            x4[rf] = x * 4;                       // 12x mod 8 == 4x mod 8
        }
        for (int o = 0; o < 10; ++o) {
            f32x4 acc1[2][2];
            #pragma unroll
            for (int jf = 0; jf < 2; ++jf)
                #pragma unroll
                for (int rf = 0; rf < 2; ++rf) acc1[jf][rf] = (f32x4){0.f, 0.f, 0.f, 0.f};
            #pragma unroll
            for (int ks = 0; ks < 4; ++ks) {
                #pragma unroll
                for (int jf = 0; jf < 2; ++jf) {
                    int j = w * 32 + jf * 16 + l16;
                    s16x8 af = *(const s16x8*)&Ut[(size_t)o * 16384 +
                                (size_t)j * 128 + ks * 32 + kq * 8];
                    #pragma unroll
                    for (int rf = 0; rf < 2; ++rf)
                        acc1[jf][rf] = mfma16(af, bh[rf][ks], acc1[jf][rf]);
                }
            }
            #pragma unroll
            for (int jf = 0; jf < 2; ++jf) {
                int j0 = w * 32 + jf * 16 + kq * 4;
                int g = j0 >> 3, sub = j0 & 7;
                #pragma unroll
                for (int rf = 0; rf < 2; ++rf) {
                    int key = (x4[rf] + o) & 7;
                    s16x4 pk;
                    #pragma unroll
                    for (int e = 0; e < 4; ++e) pk[e] = (short)f2bf(acc1[jf][rf][e]);
                    *(s16x4*)&hUb[rbase[rf] + (size_t)o * 128 + ((g ^ key) << 3) + sub] = pk;
                }
            }
        }
    }

    // ---- fused small_k: hw/tw dots from swizzled LDS tiles ----
    for (int d = tid; d < 640; d += 256) {
        int which = d / 320, rem = d - which * 320;
        int rr = rem / 10, o = rem - rr * 10;
        const unsigned short* row = (which ? Tl : Hl) + rr * 128;
        const float* wp2 = &Wl[which * 1210 + o * 121];
        float s = 0.f;
        #pragma unroll
        for (int c = 0; c < 15; ++c) {
            s16x8 v = *(const s16x8*)&row[(c ^ (rr & 7)) << 3];
            #pragma unroll
            for (int e = 0; e < 8; ++e)
                s += bf2f((unsigned short)v[e]) * wp2[c * 8 + e];
        }
        s += wp2[120];                                 // "ones" column
        int gr = r0 + rr;
        if (!which) hwp[(size_t)gr * 12 + o] = s + Wl[2420 + o];
        else        twp[(size_t)gr * 12 + o] = s;
    }
}

// ---------------------------------------------------------------------------
// K4: out = hU[b] @ t[b]^T + hw + tw + tbl.
// grid 256 blocks, XCD-remapped so each XCD owns a contiguous b-range.
// 512 thr / 8 waves (2m x 4y). B staged once (linear gload), B-frags
// hoisted; 3 m-tiles with dbuf A prefetch; stores after barrier.
// ---------------------------------------------------------------------------
__global__ __launch_bounds__(512) void main_mfma(
    const unsigned short* __restrict__ hU, const unsigned short* __restrict__ tbuf,
    const float* __restrict__ hwp, const float* __restrict__ twp,
    const float* __restrict__ tblp, float* __restrict__ out)
{
    __shared__ unsigned short Bs[256 * 128];      // 64 KB
    __shared__ unsigned short As[2][128 * 128];   // 2 x 32 KB
    const int wgid = blockIdx.x + (blockIdx.y << 3);
    const int virt = (wgid & 7) * 32 + (wgid >> 3);   // XCD k <- b in [4k,4k+4)
    const int b = virt >> 3, mg = virt & 7;
    const int tid = threadIdx.x;
    const int w = tid >> 6, lane = tid & 63;
    const int l16 = lane & 15, kq = lane >> 4;
    const int wm = w >> 2, wy = w & 3;
    const size_t hUbase = (size_t)b * 3072 * 128;
    const size_t tbase = (size_t)b * 256 * 128;

    #pragma unroll
    for (int j = 0; j < 8; ++j) {
        int off = (w * 8 + j) * 512;
        gload16(&tbuf[tbase + off + lane * 8], &Bs[off]);
    }
    {
        const size_t a0 = hUbase + (size_t)(mg * 3 * 128) * 128;
        #pragma unroll
        for (int j = 0; j < 4; ++j) {
            int off = (w * 4 + j) * 512;
            gload16(&hU[a0 + off + lane * 8], &As[0][off]);
        }
    }
    __syncthreads();

    // hoist all B fragments into registers
    s16x8 bfr[4][4];   // [ks][fy]
    #pragma unroll
    for (int ks = 0; ks < 4; ++ks)
        #pragma unroll
        for (int fy = 0; fy < 4; ++fy) {
            int row = wy * 64 + fy * 16 + l16;
            bfr[ks][fy] = *(const s16x8*)((const char*)Bs + row * 256 +
                           ((ks * 64 + kq * 16) ^ ((row & 7) << 4)));
        }

    for (int i = 0; i < 3; ++i) {
        const int m0 = (mg * 3 + i) * 128;
        if (i < 2) {                                // prefetch next A tile
            const size_t an = hUbase + (size_t)(m0 + 128) * 128;
            #pragma unroll
            for (int j = 0; j < 4; ++j) {
                int off = (w * 4 + j) * 512;
                gload16(&hU[an + off + lane * 8], &As[(i + 1) & 1][off]);
            }
        }
        const char* AsB = (const char*)&As[i & 1][0];
        f32x4 acc[4][4];
        #pragma unroll
        for (int fm = 0; fm < 4; ++fm)
            #pragma unroll
            for (int fy = 0; fy < 4; ++fy) acc[fm][fy] = (f32x4){0.f, 0.f, 0.f, 0.f};

        #pragma unroll
        for (int ks = 0; ks < 4; ++ks) {
            s16x8 af[4];
            #pragma unroll
            for (int fm = 0; fm < 4; ++fm) {
                int row = wm * 64 + fm * 16 + l16;
                af[fm] = *(const s16x8*)(AsB + row * 256 +
                          ((ks * 64 + kq * 16) ^ ((row & 7) << 4)));
            }
            #pragma unroll
            for (int fm = 0; fm < 4; ++fm)
                #pragma unroll
                for (int fy = 0; fy < 4; ++fy)
                    acc[fm][fy] = mfma16(af[fm], bfr[ks][fy], acc[fm][fy]);
        }

        __syncthreads();   // waits prefetch; stores below overlap next MFMA

        #pragma unroll
        for (int fm = 0; fm < 4; ++fm) {
            const int ml = m0 + wm * 64 + fm * 16 + kq * 4;
            if (ml < 3060) {
                const int x = ml / 12, o0 = ml % 12;      // o0 in {0,4,8}
                const int rx = b * 255 + x;
                f32x4 hv = *(const f32x4*)&hwp[(size_t)rx * 12 + o0];
                #pragma unroll
                for (int fy = 0; fy < 4; ++fy) {
                    const int y = wy * 64 + fy * 16 + l16;
                    if (y < 255) {
                        const int ry = b * 255 + y;
                        f32x4 tv = *(const f32x4*)&twp[(size_t)ry * 12 + o0];
                        int p = y - x + 1; if (p < 0) p = 0;
                        f32x4 wv = *(const f32x4*)&tblp[p * 12 + o0];
                        float* op = &out[((size_t)rx * 255 + y) * 10 + o0];
                        if (o0 < 8) {
                            float v[4];
                            #pragma unroll
                            for (int e = 0; e < 4; ++e)
                                v[e] = acc[fm][fy][e] + hv[e] + tv[e] + wv[e];
                            __builtin_memcpy(op, v, 16);
                        } else {
                            float v[2];
                            v[0] = acc[fm][fy][0] + hv[0] + tv[0] + wv[0];
                            v[1] = acc[fm][fy][1] + hv[1] + tv[1] + wv[1];
                            __builtin_memcpy(op, v, 8);
                        }
                    }
                }
            }
        }
    }
}

// ---------------------------------------------------------------------------
extern "C" void kernel_launch(void* const* d_in, const int* in_sizes, int n_in,
                              void* d_out, int out_size, void* d_ws, size_t ws_size,
                              hipStream_t stream)
{
    (void)in_sizes; (void)n_in; (void)out_size; (void)ws_size;
    const float* state  = (const float*)d_in[0];
    const float* head_w = (const float*)d_in[1];
    const float* head_b = (const float*)d_in[2];
    const float* tail_w = (const float*)d_in[3];
    const float* tail_b = (const float*)d_in[4];
    const float* U      = (const float*)d_in[5];
    const float* wtab   = (const float*)d_in[6];
    const float* cls_w  = (const float*)d_in[7];
    const float* cls_b  = (const float*)d_in[8];
    float* out = (float*)d_out;

    unsigned short* u16 = (unsigned short*)d_ws;
    unsigned short* tbuf = u16;                    // 32*256*128    = 1048576
    unsigned short* hUb  = tbuf + 1048576;         // 32*3072*128   = 12582912
    unsigned short* WP   = hUb + 12582912;         // 16*256*64     = 262144
    unsigned short* Ut   = WP + 262144;            // 10*128*128    = 163840
    float* hwp  = (float*)(Ut + 163840);           // 8160*12
    float* twp  = hwp + 97920;
    float* tblp = twp + 97920;                     // 256*12

    hipLaunchKernelGGL(convert_k, dim3(1674), dim3(256), 0, stream,
                       head_w, tail_w, U, wtab, cls_w, WP, Ut, tblp);
    hipLaunchKernelGGL(ht_mfma, dim3(255), dim3(256), 0, stream,
                       state, WP, Ut, head_b, tail_b, cls_w, cls_b,
                       tbuf, hUb, hwp, twp);
    hipLaunchKernelGGL(main_mfma, dim3(8, 32), dim3(512), 0, stream,
                       hUb, tbuf, hwp, twp, tblp, out);
}

// Round 6
// 79.849 us; speedup vs baseline: 8.5337x; 1.0902x over previous
//
#include <hip/hip_runtime.h>
#include <hip/hip_bf16.h>

using f32x4 = __attribute__((ext_vector_type(4))) float;
using s16x8 = __attribute__((ext_vector_type(8))) short;
using s16x4 = __attribute__((ext_vector_type(4))) short;

constexpr int RTOT = 32 * 255;          // 8160

__device__ inline unsigned short f2bf(float x) {
    __hip_bfloat16 b = __float2bfloat16(x);      // RNE
    return __builtin_bit_cast(unsigned short, b);
}
__device__ inline float bf2f(unsigned short u) {
    unsigned int t = ((unsigned int)u) << 16;
    return __builtin_bit_cast(float, t);
}
__device__ inline f32x4 mfma16(s16x8 a, s16x8 b, f32x4 c) {
    return __builtin_amdgcn_mfma_f32_16x16x32_bf16(a, b, c, 0, 0, 0);
}
// async global->LDS, 16B per lane; LDS dest = wave-uniform base + lane*16.
__device__ inline void gload16(const unsigned short* g, unsigned short* l) {
    __builtin_amdgcn_global_load_lds(
        (const __attribute__((address_space(1))) void*)g,
        (__attribute__((address_space(3))) void*)l, 16, 0, 0);
}

// Pre-swizzle convention (G21): for every staged [rows][128]-bf16 buffer,
// 16B-chunk c of row r is stored in global at chunk slot (c ^ (key&7)),
// key == reader's tile-local row (tile bases ≡0 mod 8 rows). Readers
// global_load_lds LINEARLY and ds_read with the same XOR.

// ---------------------------------------------------------------------------
// K0: weight conversion.
//  blocks 0..15: WP [kstep 16][n 256][kc' 8][e 8] bf16 via LDS transpose
//                (coalesced f32 reads, contiguous 16B stores).
//  blocks 16+ : Ut [o][j 128][i 128] bf16 plain (coalesced U read), and
//               tblp[256][12] width-table dot.
// ---------------------------------------------------------------------------
__global__ __launch_bounds__(256) void convert_k(
    const float* __restrict__ head_w, const float* __restrict__ tail_w,
    const float* __restrict__ U, const float* __restrict__ wtab,
    const float* __restrict__ cls_w,
    unsigned short* __restrict__ WP, unsigned short* __restrict__ Ut,
    float* __restrict__ tblp)
{
    const int tid = threadIdx.x;
    if (blockIdx.x < 16) {
        __shared__ unsigned short Lw[64][258];    // padded pitch: conflict-light
        const int ks = blockIdx.x;
        for (int idx = tid; idx < 64 * 16; idx += 256) {    // zero pad cols
            int r = idx >> 4, c = idx & 15;
            Lw[r][120 + ((c >= 8) ? 128 : 0) + (c & 7)] = 0;
        }
        for (int idx = tid; idx < 7680; idx += 256) {
            int r = idx / 120, c = idx - r * 120;
            Lw[r][c] = f2bf(head_w[(ks * 64 + r) * 120 + c]);
        }
        for (int idx = tid; idx < 7680; idx += 256) {
            int r = idx / 120, c = idx - r * 120;
            Lw[r][128 + c] = f2bf(tail_w[(ks * 64 + r) * 120 + c]);
        }
        __syncthreads();
        for (int item = tid; item < 2048; item += 256) {
            int n = item >> 3, kcp = item & 7;
            int kc = kcp ^ (n & 7);
            s16x8 v;
            #pragma unroll
            for (int e = 0; e < 8; ++e) v[e] = (short)Lw[kc * 8 + e][n];
            *(s16x8*)&WP[ks * 16384 + item * 8] = v;
        }
    } else {
        int gid = (blockIdx.x - 16) * 256 + tid;
        if (gid < 163840) {
            int j = gid & 127, i2 = (gid >> 7) & 127, o = gid >> 14;  // j fastest
            float v = (i2 < 120 && j < 120) ? U[((size_t)o * 120 + i2) * 120 + j] : 0.f;
            Ut[(size_t)o * 16384 + (size_t)j * 128 + i2] = f2bf(v);
        } else {
            int id = gid - 163840;
            if (id < 2560) {
                int p = id / 10, o = id - (id / 10) * 10;
                float s = 0.f;
                #pragma unroll
                for (int wq = 0; wq < 20; ++wq)
                    s += wtab[p * 20 + wq] * cls_w[o * 262 + 242 + wq];
                tblp[p * 12 + o] = s;
            }
        }
    }
}

// ---------------------------------------------------------------------------
// K1: h/t = leaky(state @ W + b), head+tail fused; then IN-KERNEL:
//   (a) hUb[m=x*12+o][j] = sum_i h[x][i] U[o][i][j]
//   (b) hw/tw cls_w dots
// 512 thr / 8 waves (2 waves/SIMD), grid 255 (r-tile 32). K=1024, 16x64 dbuf.
// Each wave owns 32 n-cols in the K-loop and 16 j-rows in the fused hU.
// ---------------------------------------------------------------------------
__global__ __launch_bounds__(512) void ht_mfma(
    const float* __restrict__ state, const unsigned short* __restrict__ WP,
    const unsigned short* __restrict__ Ut,
    const float* __restrict__ head_b, const float* __restrict__ tail_b,
    const float* __restrict__ cls_w, const float* __restrict__ cls_b,
    unsigned short* __restrict__ tbuf, unsigned short* __restrict__ hUb,
    float* __restrict__ hwp, float* __restrict__ twp)
{
    __shared__ unsigned short Ss[2][32 * 64];     //  2 x 4 KB: state tile bf16
    __shared__ unsigned short Ws[2][256 * 64];    //  2 x 32 KB: both W tiles
    const int r0 = blockIdx.x * 32;
    const int tid = threadIdx.x;
    const int w = tid >> 6, lane = tid & 63;
    const int l16 = lane & 15, kq = lane >> 4;
    const int srow = (tid >> 3) & 31, skc = tid & 7;
    const bool do_s = tid < 256;
    const float* sp = &state[(size_t)(r0 + srow) * 1024 + skc * 8];

    f32x4 acc[2][2];
    #pragma unroll
    for (int fn = 0; fn < 2; ++fn)
        #pragma unroll
        for (int fr = 0; fr < 2; ++fr) acc[fn][fr] = (f32x4){0.f, 0.f, 0.f, 0.f};

    // prologue
    #pragma unroll
    for (int j = 0; j < 4; ++j) {
        int off = (w * 4 + j) * 512;
        gload16(WP + off + lane * 8, &Ws[0][off]);
    }
    if (do_s) {
        f32x4 a0 = *(const f32x4*)sp;
        f32x4 a1 = *(const f32x4*)(sp + 4);
        s16x8 pk;
        #pragma unroll
        for (int e = 0; e < 4; ++e) { pk[e] = (short)f2bf(a0[e]); pk[e + 4] = (short)f2bf(a1[e]); }
        *(s16x8*)((char*)&Ss[0][0] + srow * 128 + ((skc * 16) ^ ((srow & 7) << 4))) = pk;
    }
    __syncthreads();

    for (int it = 0; it < 16; ++it) {
        const int cur = it & 1;
        f32x4 a0, a1;
        if (it < 15) {
            #pragma unroll
            for (int j = 0; j < 4; ++j) {
                int off = (w * 4 + j) * 512;
                gload16(WP + (it + 1) * 16384 + off + lane * 8, &Ws[cur ^ 1][off]);
            }
            if (do_s) {
                a0 = *(const f32x4*)(sp + (it + 1) * 64);
                a1 = *(const f32x4*)(sp + (it + 1) * 64 + 4);
            }
        }
        const char* SsB = (const char*)&Ss[cur][0];
        const char* WsB = (const char*)&Ws[cur][0];
        s16x8 bf[2][2];
        #pragma unroll
        for (int fr = 0; fr < 2; ++fr) {
            int rr = fr * 16 + l16;
            #pragma unroll
            for (int ks = 0; ks < 2; ++ks)
                bf[fr][ks] = *(const s16x8*)(SsB + rr * 128 + ((ks * 64 + kq * 16) ^ ((rr & 7) << 4)));
        }
        #pragma unroll
        for (int fn = 0; fn < 2; ++fn) {
            int n = w * 32 + fn * 16 + l16;
            #pragma unroll
            for (int ks = 0; ks < 2; ++ks) {
                s16x8 af = *(const s16x8*)(WsB + n * 128 + ((ks * 64 + kq * 16) ^ ((n & 7) << 4)));
                #pragma unroll
                for (int fr = 0; fr < 2; ++fr)
                    acc[fn][fr] = mfma16(af, bf[fr][ks], acc[fn][fr]);
            }
        }
        if (it < 15 && do_s) {
            s16x8 pk;
            #pragma unroll
            for (int e = 0; e < 4; ++e) { pk[e] = (short)f2bf(a0[e]); pk[e + 4] = (short)f2bf(a1[e]); }
            *(s16x8*)((char*)&Ss[cur ^ 1][0] + srow * 128 + ((skc * 16) ^ ((srow & 7) << 4))) = pk;
        }
        __syncthreads();
    }

    // ---- epilogue: bias + leaky -> swizzled LDS tiles (+ tbuf global) ----
    unsigned short* Hl = &Ws[0][0];                   // [32][128] key r&7
    unsigned short* Tl = &Ws[1][0];                   // [32][128] key r&7
    #pragma unroll
    for (int fn = 0; fn < 2; ++fn) {
        const int n0 = w * 32 + fn * 16 + kq * 4;     // wave-uniform isT
        const int isT = n0 >= 128;
        const int c0 = n0 & 127;
        const int g = c0 >> 3, sub = c0 & 7;
        const float* bp = isT ? tail_b : head_b;
        unsigned short* dstl = isT ? Tl : Hl;
        #pragma unroll
        for (int fr = 0; fr < 2; ++fr) {
            const int rloc = fr * 16 + l16;
            const int r = r0 + rloc;
            s16x4 pk;
            #pragma unroll
            for (int e = 0; e < 4; ++e) {
                float bv = (c0 + e < 120) ? bp[c0 + e] : 0.f;
                float z = acc[fn][fr][e] + bv;
                z = (z >= 0.f) ? z : 0.01f * z;
                pk[e] = (short)f2bf(z);
            }
            *(s16x4*)&dstl[rloc * 128 + ((g ^ (rloc & 7)) << 3) + sub] = pk;
            if (isT) {
                int bq = r / 255, x = r - bq * 255;
                *(s16x4*)&tbuf[((size_t)bq * 256 + x) * 128 + ((g ^ (x & 7)) << 3) + sub] = pk;
            }
        }
    }
    __syncthreads();

    // stage cls_w slices for the hw/tw dots (region after Hl inside Ws[0])
    float* Wl = (float*)&Ws[0][4096];     // 2430 f32: [which][o][121] + cls_b[10]
    for (int idx = tid; idx < 2430; idx += 512) {
        if (idx < 2420) {
            int which = idx / 1210, rem = idx - which * 1210;
            int o = rem / 121, i = rem - o * 121;
            Wl[idx] = cls_w[o * 262 + which * 121 + i];
        } else Wl[idx] = cls_b[idx - 2420];
    }
    __syncthreads();

    // ---- fused hU: D[j,r] = Ut[o] . h^T, straight to pre-swizzled hUb ----
    {
        s16x8 bh[2][4];   // h B-frags [rf][ks]
        #pragma unroll
        for (int rf = 0; rf < 2; ++rf) {
            int rr = rf * 16 + l16;
            #pragma unroll
            for (int ks = 0; ks < 4; ++ks)
                bh[rf][ks] = *(const s16x8*)((const char*)Hl + rr * 256 +
                              ((ks * 64 + kq * 16) ^ ((rr & 7) << 4)));
        }
        size_t rbase[2]; int x4[2];
        #pragma unroll
        for (int rf = 0; rf < 2; ++rf) {
            int gr = r0 + rf * 16 + l16;
            int bq = gr / 255, x = gr - bq * 255;
            rbase[rf] = ((size_t)bq * 3072 + x * 12) * 128;
            x4[rf] = x * 4;                       // 12x mod 8 == 4x mod 8
        }
        const int j = w * 16 + l16;
        const int j0 = w * 16 + kq * 4;
        const int g2 = j0 >> 3, sub2 = j0 & 7;
        for (int o = 0; o < 10; ++o) {
            f32x4 acc1[2];
            #pragma unroll
            for (int rf = 0; rf < 2; ++rf) acc1[rf] = (f32x4){0.f, 0.f, 0.f, 0.f};
            #pragma unroll
            for (int ks = 0; ks < 4; ++ks) {
                s16x8 af = *(const s16x8*)&Ut[(size_t)o * 16384 +
                            (size_t)j * 128 + ks * 32 + kq * 8];
                #pragma unroll
                for (int rf = 0; rf < 2; ++rf)
                    acc1[rf] = mfma16(af, bh[rf][ks], acc1[rf]);
            }
            #pragma unroll
            for (int rf = 0; rf < 2; ++rf) {
                int key = (x4[rf] + o) & 7;
                s16x4 pk;
                #pragma unroll
                for (int e = 0; e < 4; ++e) pk[e] = (short)f2bf(acc1[rf][e]);
                *(s16x4*)&hUb[rbase[rf] + (size_t)o * 128 + ((g2 ^ key) << 3) + sub2] = pk;
            }
        }
    }

    // ---- fused small_k: hw/tw dots from swizzled LDS tiles ----
    for (int d = tid; d < 640; d += 512) {
        int which = d / 320, rem = d - which * 320;
        int rr = rem / 10, o = rem - rr * 10;
        const unsigned short* row = (which ? Tl : Hl) + rr * 128;
        const float* wp2 = &Wl[which * 1210 + o * 121];
        float s = 0.f;
        #pragma unroll
        for (int c = 0; c < 15; ++c) {
            s16x8 v = *(const s16x8*)&row[(c ^ (rr & 7)) << 3];
            #pragma unroll
            for (int e = 0; e < 8; ++e)
                s += bf2f((unsigned short)v[e]) * wp2[c * 8 + e];
        }
        s += wp2[120];                                 // "ones" column
        int gr = r0 + rr;
        if (!which) hwp[(size_t)gr * 12 + o] = s + Wl[2420 + o];
        else        twp[(size_t)gr * 12 + o] = s;
    }
}

// ---------------------------------------------------------------------------
// K4: out = hU[b] @ t[b]^T + hw + tw + tbl.
// grid 256 blocks (XCD-remapped), 512 thr / 8 waves (2m x 4y). B staged once,
// B-frags hoisted; 3 m-tiles with dbuf A prefetch; stores after barrier.
// tw/tbl/hw epilogue operands staged in LDS (epilogue fully LDS-fed).
// ---------------------------------------------------------------------------
__global__ __launch_bounds__(512) void main_mfma(
    const unsigned short* __restrict__ hU, const unsigned short* __restrict__ tbuf,
    const float* __restrict__ hwp, const float* __restrict__ twp,
    const float* __restrict__ tblp, float* __restrict__ out)
{
    __shared__ unsigned short Bs[256 * 128];      // 64 KB
    __shared__ unsigned short As[2][128 * 128];   // 2 x 32 KB
    __shared__ float Ts[3060];                    // tw rows of this b
    __shared__ float Tb[3072];                    // tbl
    __shared__ float Hw[384];                     // hw rows x in [mg*32,mg*32+32)
    const int wgid = blockIdx.x + (blockIdx.y << 3);
    const int virt = (wgid & 7) * 32 + (wgid >> 3);   // XCD k <- b in [4k,4k+4)
    const int b = virt >> 3, mg = virt & 7;
    const int tid = threadIdx.x;
    const int w = tid >> 6, lane = tid & 63;
    const int l16 = lane & 15, kq = lane >> 4;
    const int wm = w >> 2, wy = w & 3;
    const size_t hUbase = (size_t)b * 3072 * 128;
    const size_t tbase = (size_t)b * 256 * 128;

    #pragma unroll
    for (int j = 0; j < 8; ++j) {
        int off = (w * 8 + j) * 512;
        gload16(&tbuf[tbase + off + lane * 8], &Bs[off]);
    }
    {
        const size_t a0 = hUbase + (size_t)(mg * 3 * 128) * 128;
        #pragma unroll
        for (int j = 0; j < 4; ++j) {
            int off = (w * 4 + j) * 512;
            gload16(&hU[a0 + off + lane * 8], &As[0][off]);
        }
    }
    // stage epilogue operands (overlaps the async gloads above)
    {
        const float* twb = twp + (size_t)b * 3060;
        for (int idx = tid; idx < 3060; idx += 512) Ts[idx] = twb[idx];
        for (int idx = tid; idx < 3072; idx += 512) Tb[idx] = tblp[idx];
        if (tid < 384 && mg * 384 + tid < 3060)
            Hw[tid] = hwp[(size_t)b * 3060 + mg * 384 + tid];
    }
    __syncthreads();

    // hoist all B fragments into registers
    s16x8 bfr[4][4];   // [ks][fy]
    #pragma unroll
    for (int ks = 0; ks < 4; ++ks)
        #pragma unroll
        for (int fy = 0; fy < 4; ++fy) {
            int row = wy * 64 + fy * 16 + l16;
            bfr[ks][fy] = *(const s16x8*)((const char*)Bs + row * 256 +
                           ((ks * 64 + kq * 16) ^ ((row & 7) << 4)));
        }

    for (int i = 0; i < 3; ++i) {
        const int m0 = (mg * 3 + i) * 128;
        if (i < 2) {                                // prefetch next A tile
            const size_t an = hUbase + (size_t)(m0 + 128) * 128;
            #pragma unroll
            for (int j = 0; j < 4; ++j) {
                int off = (w * 4 + j) * 512;
                gload16(&hU[an + off + lane * 8], &As[(i + 1) & 1][off]);
            }
        }
        const char* AsB = (const char*)&As[i & 1][0];
        f32x4 acc[4][4];
        #pragma unroll
        for (int fm = 0; fm < 4; ++fm)
            #pragma unroll
            for (int fy = 0; fy < 4; ++fy) acc[fm][fy] = (f32x4){0.f, 0.f, 0.f, 0.f};

        __builtin_amdgcn_s_setprio(1);
        #pragma unroll
        for (int ks = 0; ks < 4; ++ks) {
            s16x8 af[4];
            #pragma unroll
            for (int fm = 0; fm < 4; ++fm) {
                int row = wm * 64 + fm * 16 + l16;
                af[fm] = *(const s16x8*)(AsB + row * 256 +
                          ((ks * 64 + kq * 16) ^ ((row & 7) << 4)));
            }
            #pragma unroll
            for (int fm = 0; fm < 4; ++fm)
                #pragma unroll
                for (int fy = 0; fy < 4; ++fy)
                    acc[fm][fy] = mfma16(af[fm], bfr[ks][fy], acc[fm][fy]);
        }
        __builtin_amdgcn_s_setprio(0);

        __syncthreads();   // waits prefetch; stores below overlap next MFMA

        #pragma unroll
        for (int fm = 0; fm < 4; ++fm) {
            const int ml = m0 + wm * 64 + fm * 16 + kq * 4;
            if (ml < 3060) {
                const int x = ml / 12, o0 = ml % 12;      // o0 in {0,4,8}
                const int rx = b * 255 + x;
                f32x4 hv = *(const f32x4*)&Hw[(x - mg * 32) * 12 + o0];
                #pragma unroll
                for (int fy = 0; fy < 4; ++fy) {
                    const int y = wy * 64 + fy * 16 + l16;
                    if (y < 255) {
                        f32x4 tv = *(const f32x4*)&Ts[y * 12 + o0];
                        int p = y - x + 1; if (p < 0) p = 0;
                        f32x4 wv = *(const f32x4*)&Tb[p * 12 + o0];
                        float* op = &out[((size_t)rx * 255 + y) * 10 + o0];
                        if (o0 < 8) {
                            float v[4];
                            #pragma unroll
                            for (int e = 0; e < 4; ++e)
                                v[e] = acc[fm][fy][e] + hv[e] + tv[e] + wv[e];
                            __builtin_memcpy(op, v, 16);
                        } else {
                            float v[2];
                            v[0] = acc[fm][fy][0] + hv[0] + tv[0] + wv[0];
                            v[1] = acc[fm][fy][1] + hv[1] + tv[1] + wv[1];
                            __builtin_memcpy(op, v, 8);
                        }
                    }
                }
            }
        }
    }
}

// ---------------------------------------------------------------------------
extern "C" void kernel_launch(void* const* d_in, const int* in_sizes, int n_in,
                              void* d_out, int out_size, void* d_ws, size_t ws_size,
                              hipStream_t stream)
{
    (void)in_sizes; (void)n_in; (void)out_size; (void)ws_size;
    const float* state  = (const float*)d_in[0];
    const float* head_w = (const float*)d_in[1];
    const float* head_b = (const float*)d_in[2];
    const float* tail_w = (const float*)d_in[3];
    const float* tail_b = (const float*)d_in[4];
    const float* U      = (const float*)d_in[5];
    const float* wtab   = (const float*)d_in[6];
    const float* cls_w  = (const float*)d_in[7];
    const float* cls_b  = (const float*)d_in[8];
    float* out = (float*)d_out;

    unsigned short* u16 = (unsigned short*)d_ws;
    unsigned short* tbuf = u16;                    // 32*256*128    = 1048576
    unsigned short* hUb  = tbuf + 1048576;         // 32*3072*128   = 12582912
    unsigned short* WP   = hUb + 12582912;         // 16*256*64     = 262144
    unsigned short* Ut   = WP + 262144;            // 10*128*128    = 163840
    float* hwp  = (float*)(Ut + 163840);           // 8160*12
    float* twp  = hwp + 97920;
    float* tblp = twp + 97920;                     // 256*12

    hipLaunchKernelGGL(convert_k, dim3(666), dim3(256), 0, stream,
                       head_w, tail_w, U, wtab, cls_w, WP, Ut, tblp);
    hipLaunchKernelGGL(ht_mfma, dim3(255), dim3(512), 0, stream,
                       state, WP, Ut, head_b, tail_b, cls_w, cls_b,
                       tbuf, hUb, hwp, twp);
    hipLaunchKernelGGL(main_mfma, dim3(8, 32), dim3(512), 0, stream,
                       hUb, tbuf, hwp, twp, tblp, out);
}

// Round 7
// 76.162 us; speedup vs baseline: 8.9468x; 1.0484x over previous
//
#include <hip/hip_runtime.h>
#include <hip/hip_bf16.h>

using f32x4 = __attribute__((ext_vector_type(4))) float;
using s16x8 = __attribute__((ext_vector_type(8))) short;
using s16x4 = __attribute__((ext_vector_type(4))) short;

constexpr int RTOT = 32 * 255;          // 8160

__device__ inline unsigned short f2bf(float x) {
    __hip_bfloat16 b = __float2bfloat16(x);      // RNE
    return __builtin_bit_cast(unsigned short, b);
}
__device__ inline float bf2f(unsigned short u) {
    unsigned int t = ((unsigned int)u) << 16;
    return __builtin_bit_cast(float, t);
}
__device__ inline f32x4 mfma16(s16x8 a, s16x8 b, f32x4 c) {
    return __builtin_amdgcn_mfma_f32_16x16x32_bf16(a, b, c, 0, 0, 0);
}
// async global->LDS, 16B per lane; LDS dest = wave-uniform base + lane*16.
__device__ inline void gload16(const unsigned short* g, unsigned short* l) {
    __builtin_amdgcn_global_load_lds(
        (const __attribute__((address_space(1))) void*)g,
        (__attribute__((address_space(3))) void*)l, 16, 0, 0);
}

// Pre-swizzle convention (G21): for every staged [rows][128]-bf16 buffer,
// 16B-chunk c of row r is stored in global at chunk slot (c ^ (key&7)),
// key == reader's tile-local row (tile bases ≡0 mod 8 rows). Readers
// global_load_lds LINEARLY and ds_read with the same XOR.

// ---------------------------------------------------------------------------
// K0: weight conversion.
//  blocks 0..15: WP [kstep 16][n 256][kc' 8][e 8] bf16 via LDS transpose.
//  blocks 16+ : Ut [o][j 128][i 128] bf16 plain, and tblp[256][12].
// ---------------------------------------------------------------------------
__global__ __launch_bounds__(256) void convert_k(
    const float* __restrict__ head_w, const float* __restrict__ tail_w,
    const float* __restrict__ U, const float* __restrict__ wtab,
    const float* __restrict__ cls_w,
    unsigned short* __restrict__ WP, unsigned short* __restrict__ Ut,
    float* __restrict__ tblp)
{
    const int tid = threadIdx.x;
    if (blockIdx.x < 16) {
        __shared__ unsigned short Lw[64][258];    // padded pitch: conflict-light
        const int ks = blockIdx.x;
        for (int idx = tid; idx < 64 * 16; idx += 256) {    // zero pad cols
            int r = idx >> 4, c = idx & 15;
            Lw[r][120 + ((c >= 8) ? 128 : 0) + (c & 7)] = 0;
        }
        for (int idx = tid; idx < 7680; idx += 256) {
            int r = idx / 120, c = idx - r * 120;
            Lw[r][c] = f2bf(head_w[(ks * 64 + r) * 120 + c]);
        }
        for (int idx = tid; idx < 7680; idx += 256) {
            int r = idx / 120, c = idx - r * 120;
            Lw[r][128 + c] = f2bf(tail_w[(ks * 64 + r) * 120 + c]);
        }
        __syncthreads();
        for (int item = tid; item < 2048; item += 256) {
            int n = item >> 3, kcp = item & 7;
            int kc = kcp ^ (n & 7);
            s16x8 v;
            #pragma unroll
            for (int e = 0; e < 8; ++e) v[e] = (short)Lw[kc * 8 + e][n];
            *(s16x8*)&WP[ks * 16384 + item * 8] = v;
        }
    } else {
        int gid = (blockIdx.x - 16) * 256 + tid;
        if (gid < 163840) {
            int j = gid & 127, i2 = (gid >> 7) & 127, o = gid >> 14;  // j fastest
            float v = (i2 < 120 && j < 120) ? U[((size_t)o * 120 + i2) * 120 + j] : 0.f;
            Ut[(size_t)o * 16384 + (size_t)j * 128 + i2] = f2bf(v);
        } else {
            int id = gid - 163840;
            if (id < 2560) {
                int p = id / 10, o = id - (id / 10) * 10;
                float s = 0.f;
                #pragma unroll
                for (int wq = 0; wq < 20; ++wq)
                    s += wtab[p * 20 + wq] * cls_w[o * 262 + 242 + wq];
                tblp[p * 12 + o] = s;
            }
        }
    }
}

// ---------------------------------------------------------------------------
// K1: h/t = leaky(state @ W + b), head+tail fused; epilogue stores BOTH
// hbuf and tbuf ([32][256][128] pre-swizzled, key x&7) + hw/tw cls_w dots.
// 512 thr / 8 waves, grid 255 (r-tile 32). K=1024, 16x64 dbuf.
// ---------------------------------------------------------------------------
__global__ __launch_bounds__(512) void ht_mfma(
    const float* __restrict__ state, const unsigned short* __restrict__ WP,
    const float* __restrict__ head_b, const float* __restrict__ tail_b,
    const float* __restrict__ cls_w, const float* __restrict__ cls_b,
    unsigned short* __restrict__ hbuf, unsigned short* __restrict__ tbuf,
    float* __restrict__ hwp, float* __restrict__ twp)
{
    __shared__ unsigned short Ss[2][32 * 64];     //  2 x 4 KB: state tile bf16
    __shared__ unsigned short Ws[2][256 * 64];    //  2 x 32 KB: both W tiles
    const int r0 = blockIdx.x * 32;
    const int tid = threadIdx.x;
    const int w = tid >> 6, lane = tid & 63;
    const int l16 = lane & 15, kq = lane >> 4;
    const int srow = (tid >> 3) & 31, skc = tid & 7;
    const bool do_s = tid < 256;
    const float* sp = &state[(size_t)(r0 + srow) * 1024 + skc * 8];

    f32x4 acc[2][2];
    #pragma unroll
    for (int fn = 0; fn < 2; ++fn)
        #pragma unroll
        for (int fr = 0; fr < 2; ++fr) acc[fn][fr] = (f32x4){0.f, 0.f, 0.f, 0.f};

    // prologue
    #pragma unroll
    for (int j = 0; j < 4; ++j) {
        int off = (w * 4 + j) * 512;
        gload16(WP + off + lane * 8, &Ws[0][off]);
    }
    if (do_s) {
        f32x4 a0 = *(const f32x4*)sp;
        f32x4 a1 = *(const f32x4*)(sp + 4);
        s16x8 pk;
        #pragma unroll
        for (int e = 0; e < 4; ++e) { pk[e] = (short)f2bf(a0[e]); pk[e + 4] = (short)f2bf(a1[e]); }
        *(s16x8*)((char*)&Ss[0][0] + srow * 128 + ((skc * 16) ^ ((srow & 7) << 4))) = pk;
    }
    __syncthreads();

    for (int it = 0; it < 16; ++it) {
        const int cur = it & 1;
        f32x4 a0, a1;
        if (it < 15) {
            #pragma unroll
            for (int j = 0; j < 4; ++j) {
                int off = (w * 4 + j) * 512;
                gload16(WP + (it + 1) * 16384 + off + lane * 8, &Ws[cur ^ 1][off]);
            }
            if (do_s) {
                a0 = *(const f32x4*)(sp + (it + 1) * 64);
                a1 = *(const f32x4*)(sp + (it + 1) * 64 + 4);
            }
        }
        const char* SsB = (const char*)&Ss[cur][0];
        const char* WsB = (const char*)&Ws[cur][0];
        s16x8 bf[2][2];
        #pragma unroll
        for (int fr = 0; fr < 2; ++fr) {
            int rr = fr * 16 + l16;
            #pragma unroll
            for (int ks = 0; ks < 2; ++ks)
                bf[fr][ks] = *(const s16x8*)(SsB + rr * 128 + ((ks * 64 + kq * 16) ^ ((rr & 7) << 4)));
        }
        #pragma unroll
        for (int fn = 0; fn < 2; ++fn) {
            int n = w * 32 + fn * 16 + l16;
            #pragma unroll
            for (int ks = 0; ks < 2; ++ks) {
                s16x8 af = *(const s16x8*)(WsB + n * 128 + ((ks * 64 + kq * 16) ^ ((n & 7) << 4)));
                #pragma unroll
                for (int fr = 0; fr < 2; ++fr)
                    acc[fn][fr] = mfma16(af, bf[fr][ks], acc[fn][fr]);
            }
        }
        if (it < 15 && do_s) {
            s16x8 pk;
            #pragma unroll
            for (int e = 0; e < 4; ++e) { pk[e] = (short)f2bf(a0[e]); pk[e + 4] = (short)f2bf(a1[e]); }
            *(s16x8*)((char*)&Ss[cur ^ 1][0] + srow * 128 + ((skc * 16) ^ ((srow & 7) << 4))) = pk;
        }
        __syncthreads();
    }

    // ---- epilogue: bias + leaky -> swizzled LDS tiles + hbuf/tbuf global ----
    unsigned short* Hl = &Ws[0][0];                   // [32][128] key r&7
    unsigned short* Tl = &Ws[1][0];                   // [32][128] key r&7
    #pragma unroll
    for (int fn = 0; fn < 2; ++fn) {
        const int n0 = w * 32 + fn * 16 + kq * 4;     // wave-uniform isT
        const int isT = n0 >= 128;
        const int c0 = n0 & 127;
        const int g = c0 >> 3, sub = c0 & 7;
        const float* bp = isT ? tail_b : head_b;
        unsigned short* dstl = isT ? Tl : Hl;
        unsigned short* dstg = isT ? tbuf : hbuf;
        #pragma unroll
        for (int fr = 0; fr < 2; ++fr) {
            const int rloc = fr * 16 + l16;
            const int r = r0 + rloc;
            s16x4 pk;
            #pragma unroll
            for (int e = 0; e < 4; ++e) {
                float bv = (c0 + e < 120) ? bp[c0 + e] : 0.f;
                float z = acc[fn][fr][e] + bv;
                z = (z >= 0.f) ? z : 0.01f * z;
                pk[e] = (short)f2bf(z);
            }
            *(s16x4*)&dstl[rloc * 128 + ((g ^ (rloc & 7)) << 3) + sub] = pk;
            {
                int bq = r / 255, x = r - bq * 255;
                *(s16x4*)&dstg[((size_t)bq * 256 + x) * 128 + ((g ^ (x & 7)) << 3) + sub] = pk;
            }
        }
    }
    __syncthreads();

    // stage cls_w slices for the hw/tw dots
    float* Wl = (float*)&Ws[0][4096];     // 2430 f32: [which][o][121] + cls_b[10]
    for (int idx = tid; idx < 2430; idx += 512) {
        if (idx < 2420) {
            int which = idx / 1210, rem = idx - which * 1210;
            int o = rem / 121, i = rem - o * 121;
            Wl[idx] = cls_w[o * 262 + which * 121 + i];
        } else Wl[idx] = cls_b[idx - 2420];
    }
    __syncthreads();

    for (int d = tid; d < 640; d += 512) {
        int which = d / 320, rem = d - which * 320;
        int rr = rem / 10, o = rem - rr * 10;
        const unsigned short* row = (which ? Tl : Hl) + rr * 128;
        const float* wp2 = &Wl[which * 1210 + o * 121];
        float s = 0.f;
        #pragma unroll
        for (int c = 0; c < 15; ++c) {
            s16x8 v = *(const s16x8*)&row[(c ^ (rr & 7)) << 3];
            #pragma unroll
            for (int e = 0; e < 8; ++e)
                s += bf2f((unsigned short)v[e]) * wp2[c * 8 + e];
        }
        s += wp2[120];                                 // "ones" column
        int gr = r0 + rr;
        if (!which) hwp[(size_t)gr * 12 + o] = s + Wl[2420 + o];
        else        twp[(size_t)gr * 12 + o] = s;
    }
}

// ---------------------------------------------------------------------------
// K4: out = (h U) t^T + hw + tw + tbl, hU computed IN-KERNEL (no hUb buffer).
// grid 256 (XCD-remapped), 512 thr / 8 waves (phase2: 2m x 4y).
// Phase 0: stage t (64K) + h (8K) + epilogue f32; hoist t/h frags to regs.
// Phase 1: hU tile (384x128) = Ut[o] x h^T via MFMA -> swizzled LDS (96K,
//          aliases the staging buffers).
// Phase 2: 3 m-tiles of 128: A-frags from LDS, MFMA vs hoisted t-frags,
//          fused epilogue, stores.
// ---------------------------------------------------------------------------
__global__ __launch_bounds__(512) void main_mfma(
    const unsigned short* __restrict__ hbuf, const unsigned short* __restrict__ tbuf,
    const unsigned short* __restrict__ Ut,
    const float* __restrict__ hwp, const float* __restrict__ twp,
    const float* __restrict__ tblp, float* __restrict__ out)
{
    __shared__ __align__(16) char smem[124416];
    unsigned short* hUs = (unsigned short*)smem;          // 384 rows x 256B = 96K
    unsigned short* Bs  = (unsigned short*)smem;          // alias: 64K staging
    unsigned short* Hs  = (unsigned short*)(smem + 65536);// alias: 8K staging
    float* Ts = (float*)(smem + 98304);                   // tw rows of b (3060)
    float* Tb = (float*)(smem + 110592);                  // tbl (3072)
    float* Hw = (float*)(smem + 122880);                  // hw (384)

    const int wgid = blockIdx.x + (blockIdx.y << 3);
    const int virt = (wgid & 7) * 32 + (wgid >> 3);       // XCD k <- b in [4k,4k+4)
    const int b = virt >> 3, mg = virt & 7;
    const int tid = threadIdx.x;
    const int w = tid >> 6, lane = tid & 63;
    const int l16 = lane & 15, kq = lane >> 4;
    const int wm = w >> 2, wy = w & 3;
    const size_t tbase = (size_t)b * 256 * 128;
    const size_t hbase = ((size_t)b * 256 + mg * 32) * 128;

    // ---- phase 0: staging ----
    #pragma unroll
    for (int j = 0; j < 8; ++j) {
        int off = (w * 8 + j) * 512;
        gload16(&tbuf[tbase + off + lane * 8], &Bs[off]);
    }
    gload16(&hbuf[hbase + (size_t)(w * 64 + lane) * 8], &Hs[w * 512]);
    {
        const float* twb = twp + (size_t)b * 3060;
        for (int idx = tid; idx < 3060; idx += 512) Ts[idx] = twb[idx];
        for (int idx = tid; idx < 3072; idx += 512) Tb[idx] = tblp[idx];
        if (tid < 384) {
            int mgl = mg * 384 + tid;
            Hw[tid] = (mgl < 3060) ? hwp[(size_t)b * 3060 + mgl] : 0.f;
        }
    }
    __syncthreads();

    // hoist t fragments (phase-2 B) and h fragments (phase-1 B) to registers
    s16x8 bfr[4][4];   // [ks][fy]
    #pragma unroll
    for (int ks = 0; ks < 4; ++ks)
        #pragma unroll
        for (int fy = 0; fy < 4; ++fy) {
            int row = wy * 64 + fy * 16 + l16;
            bfr[ks][fy] = *(const s16x8*)((const char*)Bs + row * 256 +
                           ((ks * 64 + kq * 16) ^ ((row & 7) << 4)));
        }
    s16x8 bh[2][4];    // [xf][ks]
    #pragma unroll
    for (int xf = 0; xf < 2; ++xf) {
        int rr = xf * 16 + l16;
        #pragma unroll
        for (int ks = 0; ks < 4; ++ks)
            bh[xf][ks] = *(const s16x8*)((const char*)Hs + rr * 256 +
                          ((ks * 64 + kq * 16) ^ ((rr & 7) << 4)));
    }
    __syncthreads();   // all staging reads done; hUs region now writable

    // ---- phase 1: hU tile -> LDS (wave w owns j in [w*16, w*16+16)) ----
    {
        const int jrow = w * 16 + l16;
        const int j0 = w * 16 + kq * 4;
        const int g2 = j0 >> 3, sub2b = (j0 & 7) * 2;     // byte sub-offset
        #pragma unroll 2
        for (int o = 0; o < 10; ++o) {
            f32x4 acc1[2];
            acc1[0] = (f32x4){0.f, 0.f, 0.f, 0.f};
            acc1[1] = (f32x4){0.f, 0.f, 0.f, 0.f};
            #pragma unroll
            for (int ks = 0; ks < 4; ++ks) {
                s16x8 af = *(const s16x8*)&Ut[(size_t)o * 16384 +
                            (size_t)jrow * 128 + ks * 32 + kq * 8];
                acc1[0] = mfma16(af, bh[0][ks], acc1[0]);
                acc1[1] = mfma16(af, bh[1][ks], acc1[1]);
            }
            #pragma unroll
            for (int xf = 0; xf < 2; ++xf) {
                int mloc = (xf * 16 + l16) * 12 + o;
                s16x4 pk;
                #pragma unroll
                for (int e = 0; e < 4; ++e) pk[e] = (short)f2bf(acc1[xf][e]);
                *(s16x4*)((char*)hUs + mloc * 256 +
                          ((g2 ^ (mloc & 7)) << 4) + sub2b) = pk;
            }
        }
    }
    __syncthreads();

    // ---- phase 2: 3 m-tiles of 128, A from LDS, fused epilogue ----
    for (int i = 0; i < 3; ++i) {
        const int mt = i * 128;
        f32x4 acc[4][4];
        #pragma unroll
        for (int fm = 0; fm < 4; ++fm)
            #pragma unroll
            for (int fy = 0; fy < 4; ++fy) acc[fm][fy] = (f32x4){0.f, 0.f, 0.f, 0.f};

        __builtin_amdgcn_s_setprio(1);
        #pragma unroll
        for (int ks = 0; ks < 4; ++ks) {
            s16x8 af[4];
            #pragma unroll
            for (int fm = 0; fm < 4; ++fm) {
                int row = mt + wm * 64 + fm * 16 + l16;
                af[fm] = *(const s16x8*)((const char*)hUs + row * 256 +
                          ((ks * 64 + kq * 16) ^ ((row & 7) << 4)));
            }
            #pragma unroll
            for (int fm = 0; fm < 4; ++fm)
                #pragma unroll
                for (int fy = 0; fy < 4; ++fy)
                    acc[fm][fy] = mfma16(af[fm], bfr[ks][fy], acc[fm][fy]);
        }
        __builtin_amdgcn_s_setprio(0);

        #pragma unroll
        for (int fm = 0; fm < 4; ++fm) {
            const int mloc = mt + wm * 64 + fm * 16 + kq * 4;
            const int xloc = mloc / 12, o0 = mloc % 12;   // o0 in {0,4,8}
            const int x = mg * 32 + xloc;
            if (x < 255) {
                const int rx = b * 255 + x;
                f32x4 hv = *(const f32x4*)&Hw[xloc * 12 + o0];
                #pragma unroll
                for (int fy = 0; fy < 4; ++fy) {
                    const int y = wy * 64 + fy * 16 + l16;
                    if (y < 255) {
                        f32x4 tv = *(const f32x4*)&Ts[y * 12 + o0];
                        int p = y - x + 1; if (p < 0) p = 0;
                        f32x4 wv = *(const f32x4*)&Tb[p * 12 + o0];
                        float* op = &out[((size_t)rx * 255 + y) * 10 + o0];
                        if (o0 < 8) {
                            float v[4];
                            #pragma unroll
                            for (int e = 0; e < 4; ++e)
                                v[e] = acc[fm][fy][e] + hv[e] + tv[e] + wv[e];
                            __builtin_memcpy(op, v, 16);
                        } else {
                            float v[2];
                            v[0] = acc[fm][fy][0] + hv[0] + tv[0] + wv[0];
                            v[1] = acc[fm][fy][1] + hv[1] + tv[1] + wv[1];
                            __builtin_memcpy(op, v, 8);
                        }
                    }
                }
            }
        }
    }
}

// ---------------------------------------------------------------------------
extern "C" void kernel_launch(void* const* d_in, const int* in_sizes, int n_in,
                              void* d_out, int out_size, void* d_ws, size_t ws_size,
                              hipStream_t stream)
{
    (void)in_sizes; (void)n_in; (void)out_size; (void)ws_size;
    const float* state  = (const float*)d_in[0];
    const float* head_w = (const float*)d_in[1];
    const float* head_b = (const float*)d_in[2];
    const float* tail_w = (const float*)d_in[3];
    const float* tail_b = (const float*)d_in[4];
    const float* U      = (const float*)d_in[5];
    const float* wtab   = (const float*)d_in[6];
    const float* cls_w  = (const float*)d_in[7];
    const float* cls_b  = (const float*)d_in[8];
    float* out = (float*)d_out;

    unsigned short* u16 = (unsigned short*)d_ws;
    unsigned short* tbuf = u16;                    // 32*256*128 = 1048576
    unsigned short* hbuf = tbuf + 1048576;         // 32*256*128 = 1048576
    unsigned short* WP   = hbuf + 1048576;         // 16*256*64  = 262144
    unsigned short* Ut   = WP + 262144;            // 10*128*128 = 163840
    float* hwp  = (float*)(Ut + 163840);           // 8160*12
    float* twp  = hwp + 97920;
    float* tblp = twp + 97920;                     // 256*12

    hipLaunchKernelGGL(convert_k, dim3(666), dim3(256), 0, stream,
                       head_w, tail_w, U, wtab, cls_w, WP, Ut, tblp);
    hipLaunchKernelGGL(ht_mfma, dim3(255), dim3(512), 0, stream,
                       state, WP, head_b, tail_b, cls_w, cls_b,
                       hbuf, tbuf, hwp, twp);
    hipLaunchKernelGGL(main_mfma, dim3(8, 32), dim3(512), 0, stream,
                       hbuf, tbuf, Ut, hwp, twp, tblp, out);
}